// Round 1
// baseline (336.807 us; speedup 1.0000x reference)
//
#include <hip/hip_runtime.h>
#include <hip/hip_bf16.h>

typedef unsigned short u16;
typedef __bf16 bf16x8 __attribute__((ext_vector_type(8)));
typedef __bf16 bf16x4 __attribute__((ext_vector_type(4)));
typedef u16 u16x8 __attribute__((ext_vector_type(8)));
typedef float f32x4 __attribute__((ext_vector_type(4)));
typedef float f32x16 __attribute__((ext_vector_type(16)));

__device__ __forceinline__ u16 f2bf(float f) {
    unsigned u = __float_as_uint(f);
    return (u16)((u + 0x7fffu + ((u >> 16) & 1u)) >> 16);
}
__device__ __forceinline__ unsigned pkbf2(float a, float b) {
    __hip_bfloat162 h = __float22bfloat162_rn(make_float2(a, b));
    return *(unsigned*)&h;
}

// async global->LDS, 16B per lane, LDS dest = wave-uniform base + lane*16
__device__ __forceinline__ void gload16(const u16* g, u16* l) {
    __builtin_amdgcn_global_load_lds(
        (const __attribute__((address_space(1))) void*)g,
        (__attribute__((address_space(3))) void*)l, 16, 0, 0);
}

// ---------------- fp32 -> bf16 convert ----------------
__global__ void cvt_bf16(const float* __restrict__ src, u16* __restrict__ dst, int n4) {
    int i = blockIdx.x * 256 + threadIdx.x;
    if (i >= n4) return;
    float4 v = *(const float4*)(src + (size_t)i * 4);
    uint2 o; o.x = pkbf2(v.x, v.y); o.y = pkbf2(v.z, v.w);
    *(uint2*)(dst + (size_t)i * 4) = o;
}

// ---------------- GEMM core: 128x128 tile, BK=32, global_load_lds dbuf ------
// m97 structure: per K-iter issue async loads for tile kt+1, ds_read + 16 MFMA
// on tile kt, single barrier (vmcnt drain) per iter.
// LDS layout linear row-major [128][32] u16 (row = 64B) — matches the
// wave-uniform-base + lane*16B write order of global_load_lds.
__device__ __forceinline__ void gemm_core(const u16* __restrict__ Ab,
                                          const u16* __restrict__ Bb, int K,
                                          f32x4 acc[4][4], int wave, int lane) {
    __shared__ u16 As[2][128 * 32];
    __shared__ u16 Bs[2][128 * 32];
    const int quad = lane >> 4, l16 = lane & 15;
    const int wr = (wave >> 1) * 64, wc = (wave & 1) * 64;

    // wave w stages rows [w*32, w*32+32): 2 calls of 16 rows each (1KB/call).
    // lane l -> row (l>>2), 16B chunk (l&3) within the 64B row.
    const int srow = lane >> 2;
    const int selem = (lane & 3) * 8;    // elems: (l&3)*16 bytes
    const u16* ga = Ab + (size_t)(wave * 32 + srow) * K + selem;
    const u16* gb = Bb + (size_t)(wave * 32 + srow) * K + selem;
    const size_t rstep = (size_t)16 * K;
    u16* la0A[2] = { &As[0][(wave * 32) * 32], &As[1][(wave * 32) * 32] };
    u16* la1A[2] = { &As[0][(wave * 32 + 16) * 32], &As[1][(wave * 32 + 16) * 32] };
    u16* la0B[2] = { &Bs[0][(wave * 32) * 32], &Bs[1][(wave * 32) * 32] };
    u16* la1B[2] = { &Bs[0][(wave * 32 + 16) * 32], &Bs[1][(wave * 32 + 16) * 32] };

    // prologue: tile 0 into buf 0
    gload16(ga,         la0A[0]);
    gload16(ga + rstep, la1A[0]);
    gload16(gb,         la0B[0]);
    gload16(gb + rstep, la1B[0]);
    __syncthreads();

    const int nk = K >> 5;
    for (int kt = 0; kt < nk; ++kt) {
        const int cur = kt & 1, nxt = cur ^ 1;
        if (kt + 1 < nk) {
            const int off = (kt + 1) * 32;
            gload16(ga + off,         la0A[nxt]);
            gload16(ga + off + rstep, la1A[nxt]);
            gload16(gb + off,         la0B[nxt]);
            gload16(gb + off + rstep, la1B[nxt]);
        }
        bf16x8 af[4], bfr[4];
#pragma unroll
        for (int mt = 0; mt < 4; ++mt)
            af[mt] = *(const bf16x8*)&As[cur][(wr + mt * 16 + l16) * 32 + quad * 8];
#pragma unroll
        for (int nt = 0; nt < 4; ++nt)
            bfr[nt] = *(const bf16x8*)&Bs[cur][(wc + nt * 16 + l16) * 32 + quad * 8];
#pragma unroll
        for (int mt = 0; mt < 4; ++mt)
#pragma unroll
            for (int nt = 0; nt < 4; ++nt)
                acc[mt][nt] = __builtin_amdgcn_mfma_f32_16x16x32_bf16(
                    af[mt], bfr[nt], acc[mt][nt], 0, 0, 0);
        __syncthreads();
    }
}

// ---------------- plain GEMM (o-proj): C = A * B^T, fp32 out ----------------
__global__ __launch_bounds__(256)
void gemm_bt(const u16* __restrict__ A, const u16* __restrict__ B,
             float* __restrict__ C, int M, int N, int K) {
    const int tid = threadIdx.x, wave = tid >> 6, lane = tid & 63;
    const int quad = lane >> 4, l16 = lane & 15;
    const int wr = (wave >> 1) * 64, wc = (wave & 1) * 64;
    const size_t bm = (size_t)blockIdx.y * 128, bn = (size_t)blockIdx.x * 128;
    f32x4 acc[4][4] = {};
    gemm_core(A + bm * K, B + bn * K, K, acc, wave, lane);
#pragma unroll
    for (int mt = 0; mt < 4; ++mt)
#pragma unroll
        for (int nt = 0; nt < 4; ++nt)
#pragma unroll
            for (int r = 0; r < 4; ++r)
                C[(bm + wr + mt * 16 + quad * 4 + r) * (size_t)N + bn + wc + nt * 16 + l16] =
                    acc[mt][nt][r];
}

// ---------------- fused QKV GEMM: RMSNorm+RoPE (q,k) / transpose (v) --------
// N-tile tn: 0..15 = q head, 16..19 = k head, 20..23 = v head. 128 cols = head dim.
__global__ __launch_bounds__(256)
void gemm_qkv(const u16* __restrict__ xb, const u16* __restrict__ wq,
              const float* __restrict__ qw, const float* __restrict__ kw,
              const float* __restrict__ fcos, const float* __restrict__ fsin,
              u16* __restrict__ qb, u16* __restrict__ kb, u16* __restrict__ vt) {
    const int tid = threadIdx.x, wave = tid >> 6, lane = tid & 63;
    const int quad = lane >> 4, l16 = lane & 15;
    const int wr = (wave >> 1) * 64, wc = (wave & 1) * 64;
    const int tn = blockIdx.x, bmb = blockIdx.y;
    f32x4 acc[4][4] = {};
    gemm_core(xb + (size_t)bmb * 128 * 2048, wq + (size_t)tn * 128 * 2048, 2048,
              acc, wave, lane);

    const int b = bmb >> 4;
    const int sbase = (bmb & 15) * 128 + wr;   // + mt*16 + quad*4 + r

    if (tn >= 20) {
        // V: bf16 + transpose store, 4 consecutive s per bf16x4
        const int kv = tn - 20;
        u16* base = vt + (size_t)(b * 4 + kv) * 128 * 2048;
#pragma unroll
        for (int mt = 0; mt < 4; ++mt) {
            int s0 = sbase + mt * 16 + quad * 4;
#pragma unroll
            for (int nt = 0; nt < 4; ++nt) {
                int col = wc + nt * 16 + l16;
                bf16x4 pv;
#pragma unroll
                for (int r = 0; r < 4; ++r) pv[r] = (__bf16)acc[mt][nt][r];
                *(bf16x4*)(base + (size_t)col * 2048 + s0) = pv;
            }
        }
        return;
    }

    // Q/K: RMSNorm + RoPE
    __shared__ float red[2][128];
    float ssq[4][4];
#pragma unroll
    for (int mt = 0; mt < 4; ++mt)
#pragma unroll
        for (int r = 0; r < 4; ++r) {
            float t = 0.f;
#pragma unroll
            for (int nt = 0; nt < 4; ++nt) t += acc[mt][nt][r] * acc[mt][nt][r];
#pragma unroll
            for (int off = 1; off <= 8; off <<= 1) t += __shfl_xor(t, off);
            ssq[mt][r] = t;
        }
    if (l16 == 0)
#pragma unroll
        for (int mt = 0; mt < 4; ++mt)
#pragma unroll
            for (int r = 0; r < 4; ++r)
                red[wave & 1][wr + mt * 16 + quad * 4 + r] = ssq[mt][r];
    __syncthreads();

    const float qscl = (tn < 16) ? 0.08838834764831845f * 1.4426950408889634f : 1.0f;
    const float* wp = (tn < 16) ? qw : kw;
    float wcol[4];
#pragma unroll
    for (int nt = 0; nt < 4; ++nt) wcol[nt] = wp[wc + nt * 16 + l16];
    u16* dstbase = (tn < 16) ? qb + (size_t)(b * 16 + tn) * 2048 * 128
                             : kb + (size_t)(b * 4 + (tn - 16)) * 2048 * 128;
    const float sgn = (l16 & 1) ? 1.f : -1.f;

#pragma unroll
    for (int mt = 0; mt < 4; ++mt) {
#pragma unroll
        for (int r = 0; r < 4; ++r) {
            int row = wr + mt * 16 + quad * 4 + r;
            float var = (red[0][row] + red[1][row]) * (1.0f / 128.0f);
            float rms = rsqrtf(var + 1.1920928955078125e-07f) * qscl;
            int s = sbase + mt * 16 + quad * 4 + r;
            const float* fc = fcos + (size_t)s * 128 + wc;
            const float* fn = fsin + (size_t)s * 128 + wc;
            u16* drow = dstbase + (size_t)s * 128 + wc;
#pragma unroll
            for (int nt = 0; nt < 4; ++nt) {
                float y = acc[mt][nt][r] * rms * wcol[nt];
                float yp = __shfl_xor(y, 1);
                float o = y * fc[nt * 16 + l16] + sgn * yp * fn[nt * 16 + l16];
                drow[nt * 16 + l16] = f2bf(o);
            }
        }
    }
}

// ---------------- flash attention v3: 32x32 mfma, reg-P, dbuf, swizzled LDS --
#define KBUF(c) ((c) * 8192)
#define VBUF(c) (16384 + (c) * 8192)
__global__ __launch_bounds__(256, 2)
void flash_attn(const u16* __restrict__ qb, const u16* __restrict__ kb,
                const u16* __restrict__ vt, u16* __restrict__ ab) {
    __shared__ u16 smem[32768];
    __shared__ float Llds[128];

    const int tid = threadIdx.x;
    const int wave = tid >> 6, lane = tid & 63;
    const int hf = lane >> 5, c32 = lane & 31;
    const int qt = blockIdx.x, hh = blockIdx.y, bb = blockIdx.z;
    const int kh = hh >> 2;

    const u16* Qbase = qb + (size_t)(bb * 16 + hh) * 2048 * 128;
    const u16* Kbase = kb + (size_t)(bb * 4 + kh) * 2048 * 128;
    const u16* Vbase = vt + (size_t)(bb * 4 + kh) * 128 * 2048;

    bf16x8 aq[8];
#pragma unroll
    for (int kq = 0; kq < 8; ++kq)
        aq[kq] = *(const bf16x8*)(Qbase +
            (size_t)(qt * 128 + wave * 32 + c32) * 128 + kq * 16 + hf * 8);

    f32x16 O[4] = {};
    float lacc = 0.f;

    const int st_key = tid >> 4, st_c16 = tid & 15;
    const int st_d = tid >> 3, st_c8 = tid & 7;

    u16x8 kreg[4], vreg[4];
#pragma unroll
    for (int it = 0; it < 4; ++it) {
        int key = st_key + it * 16, d = st_d + it * 32;
        kreg[it] = *(const u16x8*)(Kbase + (size_t)key * 128 + st_c16 * 8);
        vreg[it] = *(const u16x8*)(Vbase + (size_t)d * 2048 + st_c8 * 8);
    }
#pragma unroll
    for (int it = 0; it < 4; ++it) {
        int key = st_key + it * 16, d = st_d + it * 32;
        *(u16x8*)&smem[KBUF(0) + key * 128 + ((st_c16 ^ (key & 7)) * 8)] = kreg[it];
        *(u16x8*)&smem[VBUF(0) + d * 64 + ((st_c8 ^ (d & 7)) * 8)] = vreg[it];
    }
    __syncthreads();

    for (int kt = 0; kt < 32; ++kt) {
        const int cur = kt & 1, nxt = cur ^ 1;
        if (kt < 31) {
            const int key0n = (kt + 1) * 64;
#pragma unroll
            for (int it = 0; it < 4; ++it) {
                int key = st_key + it * 16, d = st_d + it * 32;
                kreg[it] = *(const u16x8*)(Kbase + (size_t)(key0n + key) * 128 + st_c16 * 8);
                vreg[it] = *(const u16x8*)(Vbase + (size_t)d * 2048 + key0n + st_c8 * 8);
            }
        }

        f32x16 sc[2] = {};
#pragma unroll
        for (int kq = 0; kq < 8; ++kq) {
#pragma unroll
            for (int mt = 0; mt < 2; ++mt) {
                bf16x8 kf = *(const bf16x8*)&smem[KBUF(cur) + (mt * 32 + c32) * 128 +
                                                 (((kq * 2 + hf) ^ (c32 & 7)) * 8)];
                sc[mt] = __builtin_amdgcn_mfma_f32_32x32x16_bf16(kf, aq[kq], sc[mt], 0, 0, 0);
            }
        }

        int pdw[2][8];
#pragma unroll
        for (int mt = 0; mt < 2; ++mt) {
            float p[16];
#pragma unroll
            for (int r = 0; r < 16; ++r) {
                p[r] = __builtin_amdgcn_exp2f(sc[mt][r]);
                lacc += p[r];
            }
#pragma unroll
            for (int i = 0; i < 8; ++i) pdw[mt][i] = (int)pkbf2(p[2 * i], p[2 * i + 1]);
        }

        if (kt < 31) {
#pragma unroll
            for (int it = 0; it < 4; ++it) {
                int key = st_key + it * 16, d = st_d + it * 32;
                *(u16x8*)&smem[KBUF(nxt) + key * 128 + ((st_c16 ^ (key & 7)) * 8)] = kreg[it];
                *(u16x8*)&smem[VBUF(nxt) + d * 64 + ((st_c8 ^ (d & 7)) * 8)] = vreg[it];
            }
        }

#pragma unroll
        for (int kc = 0; kc < 4; ++kc) {
            const int mt = kc >> 1, L = kc & 1;
            int s0 = hf ? pdw[mt][4 * L + 0] : pdw[mt][4 * L + 2];
            int s1 = hf ? pdw[mt][4 * L + 1] : pdw[mt][4 * L + 3];
            int r0 = __shfl_xor(s0, 32);
            int r1 = __shfl_xor(s1, 32);
            union { int i[4]; bf16x8 v; } u;
            u.i[0] = hf ? r0 : pdw[mt][4 * L + 0];
            u.i[1] = hf ? r1 : pdw[mt][4 * L + 1];
            u.i[2] = hf ? pdw[mt][4 * L + 2] : r0;
            u.i[3] = hf ? pdw[mt][4 * L + 3] : r1;
#pragma unroll
            for (int dt = 0; dt < 4; ++dt) {
                bf16x8 vf = *(const bf16x8*)&smem[VBUF(cur) + (dt * 32 + c32) * 64 +
                                                 (((kc * 2 + hf) ^ (c32 & 7)) * 8)];
                O[dt] = __builtin_amdgcn_mfma_f32_32x32x16_bf16(u.v, vf, O[dt], 0, 0, 0);
            }
        }
        __syncthreads();
    }

    float l = lacc + __shfl_xor(lacc, 32);
    if (hf == 0) Llds[wave * 32 + c32] = l;

    float inv[16];
#pragma unroll
    for (int r = 0; r < 16; ++r)
        inv[r] = __builtin_amdgcn_rcpf(Llds[wave * 32 + (r & 3) + 8 * (r >> 2) + 4 * hf]);

    u16* scr = &smem[wave * 32 * 136];
#pragma unroll
    for (int dt = 0; dt < 4; ++dt)
#pragma unroll
        for (int r = 0; r < 16; ++r) {
            int q_r = (r & 3) + 8 * (r >> 2) + 4 * hf;
            scr[q_r * 136 + dt * 32 + c32] = f2bf(O[dt][r] * inv[r]);
        }
#pragma unroll
    for (int it = 0; it < 8; ++it) {
        int f = it * 64 + lane;
        int row = f >> 4, c = f & 15;
        u16x8 v = *(const u16x8*)&scr[row * 136 + c * 8];
        int qg = qt * 128 + wave * 32 + row;
        *(u16x8*)(ab + ((size_t)(bb * 2048 + qg)) * 2048 + hh * 128 + c * 8) = v;
    }
}

// ---------------- host launch ----------------
extern "C" void kernel_launch(void* const* d_in, const int* in_sizes, int n_in,
                              void* d_out, int out_size, void* d_ws, size_t ws_size,
                              hipStream_t stream) {
    const float* x    = (const float*)d_in[0];
    const float* wqkv = (const float*)d_in[1];
    const float* wo   = (const float*)d_in[2];
    const float* qw   = (const float*)d_in[3];
    const float* kw   = (const float*)d_in[4];
    const float* fc   = (const float*)d_in[5];
    const float* fs   = (const float*)d_in[6];
    float* out = (float*)d_out;
    char* ws = (char*)d_ws;

    u16* xb    = (u16*)(ws + 0);          // 4096x2048 bf16 (16 MB)
    u16* wqkvb = (u16*)(ws + 16777216);   // 3072x2048 bf16 (12 MB)
    u16* wob   = (u16*)(ws + 29360128);   // 2048x2048 bf16 ( 8 MB)
    u16* qb    = (u16*)(ws + 37748736);   // [2,16,2048,128] (16 MB)
    u16* kb    = (u16*)(ws + 54525952);   // [2,4,2048,128]  ( 4 MB)
    u16* vt    = (u16*)(ws + 58720256);   // [2,4,128,2048]  ( 4 MB)
    u16* ab    = (u16*)(ws + 62914560);   // 4096x2048 bf16  (16 MB)

    cvt_bf16<<<8192, 256, 0, stream>>>(x, xb, 2097152);
    cvt_bf16<<<6144, 256, 0, stream>>>(wqkv, wqkvb, 1572864);
    cvt_bf16<<<4096, 256, 0, stream>>>(wo, wob, 1048576);
    gemm_qkv<<<dim3(24, 32), 256, 0, stream>>>(xb, wqkvb, qw, kw, fc, fs, qb, kb, vt);
    flash_attn<<<dim3(16, 16, 2), 256, 0, stream>>>(qb, kb, vt, ab);
    gemm_bt<<<dim3(16, 32), 256, 0, stream>>>(ab, wob, out, 4096, 2048, 2048);
}

// Round 2
// 316.954 us; speedup vs baseline: 1.0626x; 1.0626x over previous
//
#include <hip/hip_runtime.h>
#include <hip/hip_bf16.h>

typedef unsigned short u16;
typedef __bf16 bf16x8 __attribute__((ext_vector_type(8)));
typedef __bf16 bf16x4 __attribute__((ext_vector_type(4)));
typedef u16 u16x8 __attribute__((ext_vector_type(8)));
typedef float f32x4 __attribute__((ext_vector_type(4)));
typedef float f32x16 __attribute__((ext_vector_type(16)));

__device__ __forceinline__ u16 f2bf(float f) {
    unsigned u = __float_as_uint(f);
    return (u16)((u + 0x7fffu + ((u >> 16) & 1u)) >> 16);
}
__device__ __forceinline__ unsigned pkbf2(float a, float b) {
    __hip_bfloat162 h = __float22bfloat162_rn(make_float2(a, b));
    return *(unsigned*)&h;
}

// async global->LDS, 16B per lane, LDS dest = wave-uniform base + lane*16
__device__ __forceinline__ void gload16(const u16* g, u16* l) {
    __builtin_amdgcn_global_load_lds(
        (const __attribute__((address_space(1))) void*)g,
        (__attribute__((address_space(3))) void*)l, 16, 0, 0);
}

// raw barrier with compile-time scheduling fence (no vmcnt drain!)
__device__ __forceinline__ void block_sync() {
    __builtin_amdgcn_sched_barrier(0);
    __builtin_amdgcn_s_barrier();
    __builtin_amdgcn_sched_barrier(0);
}
template<int N> __device__ __forceinline__ void waitvm() {
    if constexpr (N == 0)      asm volatile("s_waitcnt vmcnt(0)" ::: "memory");
    else if constexpr (N == 6) asm volatile("s_waitcnt vmcnt(6)" ::: "memory");
    else                       asm volatile("s_waitcnt vmcnt(8)" ::: "memory");
}

// ---------------- fp32 -> bf16 convert ----------------
__global__ void cvt_bf16(const float* __restrict__ src, u16* __restrict__ dst, int n4) {
    int i = blockIdx.x * 256 + threadIdx.x;
    if (i >= n4) return;
    float4 v = *(const float4*)(src + (size_t)i * 4);
    uint2 o; o.x = pkbf2(v.x, v.y); o.y = pkbf2(v.z, v.w);
    *(uint2*)(dst + (size_t)i * 4) = o;
}

// ---------------- deep-pipelined GEMM core (256-class tile, BK=64) ----------
// LDS tile rows are 64 bf16 (128B). Physical 16B-chunk = logical ^ (row&7):
// staged by pre-swizzling the GLOBAL source column (linear LDS dest for
// global_load_lds), read back with the same XOR -> conflict-free ds_read_b128
// (64 lanes spread exactly 8 per bank-group = the b128 floor).
// Pipeline: issue next tile's loads, vmcnt(S) (counted, never 0 in steady
// state) proves current tile landed, raw barrier, compute (2 kk phases,
// setprio around MFMA cluster), raw barrier (all frag reads are consumed by
// MFMAs in-iter, so reads are complete here), next iter overwrites freed buf.
template<int ROWS>
__device__ __forceinline__ void stage_tile(const u16* __restrict__ g, int K,
                                           int k0, u16* l, int tid) {
#pragma unroll
    for (int s = 0; s < ROWS / 64; ++s) {
        int row = s * 64 + (tid >> 3);
        int sc = (tid & 7) ^ ((tid >> 3) & 7);
        gload16(g + (size_t)row * K + k0 + sc * 8, l + s * 4096 + tid * 8);
    }
}

template<int BM, int BN>
__device__ __forceinline__ void gemm_pipeline(const u16* __restrict__ Ab,
                                              const u16* __restrict__ Bb, int K,
                                              u16* sAll,
                                              f32x4 (&acc)[BM / 32][BN / 64],
                                              int tid) {
    constexpr int MR = BM / 32, NR = BN / 64;
    constexpr int TILE = (BM + BN) * 64;
    const int lane = tid & 63, wave = tid >> 6;
    const int quad = lane >> 4, l16 = lane & 15;
    const int wm = wave >> 2, wn = wave & 3;
    const int ar0 = wm * (BM / 2) + l16;
    const int br0 = wn * (BN / 4) + l16;

    u16* sA0 = sAll;        u16* sB0 = sAll + BM * 64;
    u16* sA1 = sAll + TILE; u16* sB1 = sAll + TILE + BM * 64;

    // prologue: tile 0 -> buf 0
    stage_tile<BM>(Ab, K, 0, sA0, tid);
    stage_tile<BN>(Bb, K, 0, sB0, tid);

    const int nt = K >> 6;
    for (int t = 0; t < nt; ++t) {
        const u16* cA = (t & 1) ? sA1 : sA0;
        const u16* cB = (t & 1) ? sB1 : sB0;
        if (t + 1 < nt) {
            // stage tile t+1 into the buffer freed at the end of iter t-1
            u16* nA = (t & 1) ? sA0 : sA1;
            u16* nB = (t & 1) ? sB0 : sB1;
            stage_tile<BM>(Ab, K, (t + 1) * 64, nA, tid);
            stage_tile<BN>(Bb, K, (t + 1) * 64, nB, tid);
            waitvm<(BM + BN) / 64>();   // tile t landed; t+1 stays in flight
        } else {
            waitvm<0>();                // tail drain
        }
        block_sync();                    // all waves see tile t
#pragma unroll
        for (int kk = 0; kk < 2; ++kk) {
            const int c = kk * 4 + quad;
            bf16x8 af[MR], bf[NR];
#pragma unroll
            for (int m = 0; m < MR; ++m) {
                int r = ar0 + m * 16;
                af[m] = *(const bf16x8*)&cA[r * 64 + ((c ^ (r & 7)) * 8)];
            }
#pragma unroll
            for (int n = 0; n < NR; ++n) {
                int r = br0 + n * 16;
                bf[n] = *(const bf16x8*)&cB[r * 64 + ((c ^ (r & 7)) * 8)];
            }
            __builtin_amdgcn_s_setprio(1);
#pragma unroll
            for (int m = 0; m < MR; ++m)
#pragma unroll
                for (int n = 0; n < NR; ++n)
                    acc[m][n] = __builtin_amdgcn_mfma_f32_16x16x32_bf16(
                        af[m], bf[n], acc[m][n], 0, 0, 0);
            __builtin_amdgcn_s_setprio(0);
        }
        block_sync();                    // frag reads done -> buf free
    }
}

// ---------------- o-proj GEMM: C = A * B^T, fp32 out (128x256 tile) ---------
__global__ __launch_bounds__(512, 2)
void gemm_bt(const u16* __restrict__ A, const u16* __restrict__ B,
             float* __restrict__ C, int M, int N, int K) {
    __shared__ u16 sAll[2 * (128 + 256) * 64];
    const int tid = threadIdx.x;
    const int wave = tid >> 6, lane = tid & 63;
    const int quad = lane >> 4, l16 = lane & 15;
    const int wm = wave >> 2, wn = wave & 3;
    const size_t bm = (size_t)blockIdx.y * 128, bn = (size_t)blockIdx.x * 256;
    f32x4 acc[4][4] = {};
    gemm_pipeline<128, 256>(A + bm * K, B + bn * K, K, sAll, acc, tid);
#pragma unroll
    for (int m = 0; m < 4; ++m)
#pragma unroll
        for (int n = 0; n < 4; ++n)
#pragma unroll
            for (int r = 0; r < 4; ++r)
                C[(bm + wm * 64 + m * 16 + quad * 4 + r) * (size_t)N +
                  bn + wn * 64 + n * 16 + l16] = acc[m][n][r];
}

// ---------------- fused QKV GEMM (256x256): RMSNorm+RoPE (q,k) / transpose (v)
// N-tile bx: 0..7 = Q heads (2bx,2bx+1), 8..9 = K heads, 10..11 = V heads.
__global__ __launch_bounds__(512, 2)
void gemm_qkv(const u16* __restrict__ xb, const u16* __restrict__ wq,
              const float* __restrict__ qw, const float* __restrict__ kw,
              const float* __restrict__ fcos, const float* __restrict__ fsin,
              u16* __restrict__ qb, u16* __restrict__ kb, u16* __restrict__ vt) {
    __shared__ u16 sAll[2 * (256 + 256) * 64];
    const int tid = threadIdx.x;
    const int wave = tid >> 6, lane = tid & 63;
    const int quad = lane >> 4, l16 = lane & 15;
    const int wm = wave >> 2, wn = wave & 3;
    const int bx = blockIdx.x, by = blockIdx.y;
    f32x4 acc[8][4] = {};
    gemm_pipeline<256, 256>(xb + (size_t)by * 256 * 2048,
                            wq + (size_t)bx * 256 * 2048, 2048, sAll, acc, tid);

    const int b = by >> 3;                       // batch
    const int sb = (by & 7) * 256 + wm * 128;    // seq pos base (+m*16+quad*4+r)
    const int headh = wn >> 1;                   // which head of the 2 in tile
    const int dcol0 = (wn & 1) * 64;             // dim base within head (+n*16+l16)

    if (bx >= 10) {
        // V: bf16 transpose store, 4 consecutive s per bf16x4
        const int kvh = (bx - 10) * 2 + headh;
        u16* base = vt + (size_t)(b * 4 + kvh) * 128 * 2048;
#pragma unroll
        for (int m = 0; m < 8; ++m) {
            int s0 = sb + m * 16 + quad * 4;
#pragma unroll
            for (int n = 0; n < 4; ++n) {
                int d = dcol0 + n * 16 + l16;
                bf16x4 pv;
#pragma unroll
                for (int r = 0; r < 4; ++r) pv[r] = (__bf16)acc[m][n][r];
                *(bf16x4*)(base + (size_t)d * 2048 + s0) = pv;
            }
        }
        return;
    }

    // Q/K: RMSNorm + RoPE
    float* red = (float*)sAll;   // [parity(2)][headh(2)][row(256)] partial ssq
    float ssq[8][4];
#pragma unroll
    for (int m = 0; m < 8; ++m)
#pragma unroll
        for (int r = 0; r < 4; ++r) {
            float t = 0.f;
#pragma unroll
            for (int n = 0; n < 4; ++n) t += acc[m][n][r] * acc[m][n][r];
#pragma unroll
            for (int off = 1; off <= 8; off <<= 1) t += __shfl_xor(t, off);
            ssq[m][r] = t;
        }
    if (l16 == 0)
#pragma unroll
        for (int m = 0; m < 8; ++m)
#pragma unroll
            for (int r = 0; r < 4; ++r)
                red[((wn & 1) * 2 + headh) * 256 + wm * 128 + m * 16 + quad * 4 + r] =
                    ssq[m][r];
    __syncthreads();

    const bool isQ = bx < 8;
    const float qscl = isQ ? 0.08838834764831845f * 1.4426950408889634f : 1.0f;
    const float* wp = isQ ? qw : kw;
    float wcol[4];
#pragma unroll
    for (int n = 0; n < 4; ++n) wcol[n] = wp[dcol0 + n * 16 + l16];
    u16* dstbase = isQ ? qb + (size_t)(b * 16 + bx * 2 + headh) * 2048 * 128
                       : kb + (size_t)(b * 4 + (bx - 8) * 2 + headh) * 2048 * 128;
    const float sgn = (l16 & 1) ? 1.f : -1.f;

#pragma unroll
    for (int m = 0; m < 8; ++m) {
#pragma unroll
        for (int r = 0; r < 4; ++r) {
            int rowl = wm * 128 + m * 16 + quad * 4 + r;
            float var = (red[(0 + headh) * 256 + rowl] +
                         red[(2 + headh) * 256 + rowl]) * (1.0f / 128.0f);
            float rms = rsqrtf(var + 1.1920928955078125e-07f) * qscl;
            int s = sb + m * 16 + quad * 4 + r;
            const float* fc = fcos + (size_t)s * 128 + dcol0;
            const float* fn = fsin + (size_t)s * 128 + dcol0;
            u16* drow = dstbase + (size_t)s * 128 + dcol0;
#pragma unroll
            for (int n = 0; n < 4; ++n) {
                float y = acc[m][n][r] * rms * wcol[n];
                float yp = __shfl_xor(y, 1);
                float o = y * fc[n * 16 + l16] + sgn * yp * fn[n * 16 + l16];
                drow[n * 16 + l16] = f2bf(o);
            }
        }
    }
}

// ---------------- flash attention v3: 32x32 mfma, reg-P, dbuf, swizzled LDS --
#define KBUF(c) ((c) * 8192)
#define VBUF(c) (16384 + (c) * 8192)
__global__ __launch_bounds__(256, 2)
void flash_attn(const u16* __restrict__ qb, const u16* __restrict__ kb,
                const u16* __restrict__ vt, u16* __restrict__ ab) {
    __shared__ u16 smem[32768];
    __shared__ float Llds[128];

    const int tid = threadIdx.x;
    const int wave = tid >> 6, lane = tid & 63;
    const int hf = lane >> 5, c32 = lane & 31;
    const int qt = blockIdx.x, hh = blockIdx.y, bb = blockIdx.z;
    const int kh = hh >> 2;

    const u16* Qbase = qb + (size_t)(bb * 16 + hh) * 2048 * 128;
    const u16* Kbase = kb + (size_t)(bb * 4 + kh) * 2048 * 128;
    const u16* Vbase = vt + (size_t)(bb * 4 + kh) * 128 * 2048;

    bf16x8 aq[8];
#pragma unroll
    for (int kq = 0; kq < 8; ++kq)
        aq[kq] = *(const bf16x8*)(Qbase +
            (size_t)(qt * 128 + wave * 32 + c32) * 128 + kq * 16 + hf * 8);

    f32x16 O[4] = {};
    float lacc = 0.f;

    const int st_key = tid >> 4, st_c16 = tid & 15;
    const int st_d = tid >> 3, st_c8 = tid & 7;

    u16x8 kreg[4], vreg[4];
#pragma unroll
    for (int it = 0; it < 4; ++it) {
        int key = st_key + it * 16, d = st_d + it * 32;
        kreg[it] = *(const u16x8*)(Kbase + (size_t)key * 128 + st_c16 * 8);
        vreg[it] = *(const u16x8*)(Vbase + (size_t)d * 2048 + st_c8 * 8);
    }
#pragma unroll
    for (int it = 0; it < 4; ++it) {
        int key = st_key + it * 16, d = st_d + it * 32;
        *(u16x8*)&smem[KBUF(0) + key * 128 + ((st_c16 ^ (key & 7)) * 8)] = kreg[it];
        *(u16x8*)&smem[VBUF(0) + d * 64 + ((st_c8 ^ (d & 7)) * 8)] = vreg[it];
    }
    __syncthreads();

    for (int kt = 0; kt < 32; ++kt) {
        const int cur = kt & 1, nxt = cur ^ 1;
        if (kt < 31) {
            const int key0n = (kt + 1) * 64;
#pragma unroll
            for (int it = 0; it < 4; ++it) {
                int key = st_key + it * 16, d = st_d + it * 32;
                kreg[it] = *(const u16x8*)(Kbase + (size_t)(key0n + key) * 128 + st_c16 * 8);
                vreg[it] = *(const u16x8*)(Vbase + (size_t)d * 2048 + key0n + st_c8 * 8);
            }
        }

        f32x16 sc[2] = {};
#pragma unroll
        for (int kq = 0; kq < 8; ++kq) {
#pragma unroll
            for (int mt = 0; mt < 2; ++mt) {
                bf16x8 kf = *(const bf16x8*)&smem[KBUF(cur) + (mt * 32 + c32) * 128 +
                                                 (((kq * 2 + hf) ^ (c32 & 7)) * 8)];
                sc[mt] = __builtin_amdgcn_mfma_f32_32x32x16_bf16(kf, aq[kq], sc[mt], 0, 0, 0);
            }
        }

        int pdw[2][8];
#pragma unroll
        for (int mt = 0; mt < 2; ++mt) {
            float p[16];
#pragma unroll
            for (int r = 0; r < 16; ++r) {
                p[r] = __builtin_amdgcn_exp2f(sc[mt][r]);
                lacc += p[r];
            }
#pragma unroll
            for (int i = 0; i < 8; ++i) pdw[mt][i] = (int)pkbf2(p[2 * i], p[2 * i + 1]);
        }

        if (kt < 31) {
#pragma unroll
            for (int it = 0; it < 4; ++it) {
                int key = st_key + it * 16, d = st_d + it * 32;
                *(u16x8*)&smem[KBUF(nxt) + key * 128 + ((st_c16 ^ (key & 7)) * 8)] = kreg[it];
                *(u16x8*)&smem[VBUF(nxt) + d * 64 + ((st_c8 ^ (d & 7)) * 8)] = vreg[it];
            }
        }

#pragma unroll
        for (int kc = 0; kc < 4; ++kc) {
            const int mt = kc >> 1, L = kc & 1;
            int s0 = hf ? pdw[mt][4 * L + 0] : pdw[mt][4 * L + 2];
            int s1 = hf ? pdw[mt][4 * L + 1] : pdw[mt][4 * L + 3];
            int r0 = __shfl_xor(s0, 32);
            int r1 = __shfl_xor(s1, 32);
            union { int i[4]; bf16x8 v; } u;
            u.i[0] = hf ? r0 : pdw[mt][4 * L + 0];
            u.i[1] = hf ? r1 : pdw[mt][4 * L + 1];
            u.i[2] = hf ? pdw[mt][4 * L + 2] : r0;
            u.i[3] = hf ? pdw[mt][4 * L + 3] : r1;
#pragma unroll
            for (int dt = 0; dt < 4; ++dt) {
                bf16x8 vf = *(const bf16x8*)&smem[VBUF(cur) + (dt * 32 + c32) * 64 +
                                                 (((kc * 2 + hf) ^ (c32 & 7)) * 8)];
                O[dt] = __builtin_amdgcn_mfma_f32_32x32x16_bf16(u.v, vf, O[dt], 0, 0, 0);
            }
        }
        __syncthreads();
    }

    float l = lacc + __shfl_xor(lacc, 32);
    if (hf == 0) Llds[wave * 32 + c32] = l;

    float inv[16];
#pragma unroll
    for (int r = 0; r < 16; ++r)
        inv[r] = __builtin_amdgcn_rcpf(Llds[wave * 32 + (r & 3) + 8 * (r >> 2) + 4 * hf]);

    u16* scr = &smem[wave * 32 * 136];
#pragma unroll
    for (int dt = 0; dt < 4; ++dt)
#pragma unroll
        for (int r = 0; r < 16; ++r) {
            int q_r = (r & 3) + 8 * (r >> 2) + 4 * hf;
            scr[q_r * 136 + dt * 32 + c32] = f2bf(O[dt][r] * inv[r]);
        }
#pragma unroll
    for (int it = 0; it < 8; ++it) {
        int f = it * 64 + lane;
        int row = f >> 4, c = f & 15;
        u16x8 v = *(const u16x8*)&scr[row * 136 + c * 8];
        int qg = qt * 128 + wave * 32 + row;
        *(u16x8*)(ab + ((size_t)(bb * 2048 + qg)) * 2048 + hh * 128 + c * 8) = v;
    }
}

// ---------------- host launch ----------------
extern "C" void kernel_launch(void* const* d_in, const int* in_sizes, int n_in,
                              void* d_out, int out_size, void* d_ws, size_t ws_size,
                              hipStream_t stream) {
    const float* x    = (const float*)d_in[0];
    const float* wqkv = (const float*)d_in[1];
    const float* wo   = (const float*)d_in[2];
    const float* qw   = (const float*)d_in[3];
    const float* kw   = (const float*)d_in[4];
    const float* fc   = (const float*)d_in[5];
    const float* fs   = (const float*)d_in[6];
    float* out = (float*)d_out;
    char* ws = (char*)d_ws;

    u16* xb    = (u16*)(ws + 0);          // 4096x2048 bf16 (16 MB)
    u16* wqkvb = (u16*)(ws + 16777216);   // 3072x2048 bf16 (12 MB)
    u16* wob   = (u16*)(ws + 29360128);   // 2048x2048 bf16 ( 8 MB)
    u16* qb    = (u16*)(ws + 37748736);   // [2,16,2048,128] (16 MB)
    u16* kb    = (u16*)(ws + 54525952);   // [2,4,2048,128]  ( 4 MB)
    u16* vt    = (u16*)(ws + 58720256);   // [2,4,128,2048]  ( 4 MB)
    u16* ab    = (u16*)(ws + 62914560);   // 4096x2048 bf16  (16 MB)

    cvt_bf16<<<8192, 256, 0, stream>>>(x, xb, 2097152);
    cvt_bf16<<<6144, 256, 0, stream>>>(wqkv, wqkvb, 1572864);
    cvt_bf16<<<4096, 256, 0, stream>>>(wo, wob, 1048576);
    gemm_qkv<<<dim3(12, 16), 512, 0, stream>>>(xb, wqkvb, qw, kw, fc, fs, qb, kb, vt);
    flash_attn<<<dim3(16, 16, 2), 256, 0, stream>>>(qb, kb, vt, ab);
    gemm_bt<<<dim3(8, 32), 512, 0, stream>>>(ab, wob, out, 4096, 2048, 2048);
}

// Round 5
// 313.376 us; speedup vs baseline: 1.0748x; 1.0114x over previous
//
#include <hip/hip_runtime.h>
#include <hip/hip_bf16.h>

typedef unsigned short u16;
typedef __bf16 bf16x8 __attribute__((ext_vector_type(8)));
typedef __bf16 bf16x4 __attribute__((ext_vector_type(4)));
typedef u16 u16x8 __attribute__((ext_vector_type(8)));
typedef float f32x4 __attribute__((ext_vector_type(4)));
typedef float f32x16 __attribute__((ext_vector_type(16)));

__device__ __forceinline__ u16 f2bf(float f) {
    unsigned u = __float_as_uint(f);
    return (u16)((u + 0x7fffu + ((u >> 16) & 1u)) >> 16);
}
__device__ __forceinline__ unsigned pkbf2(float a, float b) {
    __hip_bfloat162 h = __float22bfloat162_rn(make_float2(a, b));
    return *(unsigned*)&h;
}

// async global->LDS, 16B per lane, LDS dest = wave-uniform base + lane*16
__device__ __forceinline__ void gload16(const u16* g, u16* l) {
    __builtin_amdgcn_global_load_lds(
        (const __attribute__((address_space(1))) void*)g,
        (__attribute__((address_space(3))) void*)l, 16, 0, 0);
}

// raw barrier with compile-time scheduling fence (no vmcnt drain!)
__device__ __forceinline__ void block_sync() {
    __builtin_amdgcn_sched_barrier(0);
    __builtin_amdgcn_s_barrier();
    __builtin_amdgcn_sched_barrier(0);
}
template<int N> __device__ __forceinline__ void waitvm() {
    if constexpr (N == 0)      asm volatile("s_waitcnt vmcnt(0)" ::: "memory");
    else if constexpr (N == 6) asm volatile("s_waitcnt vmcnt(6)" ::: "memory");
    else                       asm volatile("s_waitcnt vmcnt(8)" ::: "memory");
}

// ---------------- fp32 -> bf16 convert ----------------
__global__ void cvt_bf16(const float* __restrict__ src, u16* __restrict__ dst, int n4) {
    int i = blockIdx.x * 256 + threadIdx.x;
    if (i >= n4) return;
    float4 v = *(const float4*)(src + (size_t)i * 4);
    uint2 o; o.x = pkbf2(v.x, v.y); o.y = pkbf2(v.z, v.w);
    *(uint2*)(dst + (size_t)i * 4) = o;
}

// ---------------- deep-pipelined GEMM core (256-class tile, BK=64) ----------
// LDS tile rows are 64 bf16 (128B). Physical 16B-chunk = logical ^ (row&7):
// staged by pre-swizzling the GLOBAL source column (linear LDS dest for
// global_load_lds), read back with the same XOR -> conflict-free ds_read_b128.
template<int ROWS>
__device__ __forceinline__ void stage_tile(const u16* __restrict__ g, int K,
                                           int k0, u16* l, int tid) {
#pragma unroll
    for (int s = 0; s < ROWS / 64; ++s) {
        int row = s * 64 + (tid >> 3);
        int sc = (tid & 7) ^ ((tid >> 3) & 7);
        gload16(g + (size_t)row * K + k0 + sc * 8, l + s * 4096 + tid * 8);
    }
}

template<int BM, int BN>
__device__ __forceinline__ void gemm_pipeline(const u16* __restrict__ Ab,
                                              const u16* __restrict__ Bb, int K,
                                              u16* sAll,
                                              f32x4 (&acc)[BM / 32][BN / 64],
                                              int tid) {
    constexpr int MR = BM / 32, NR = BN / 64;
    constexpr int TILE = (BM + BN) * 64;
    const int lane = tid & 63, wave = tid >> 6;
    const int quad = lane >> 4, l16 = lane & 15;
    const int wm = wave >> 2, wn = wave & 3;
    const int ar0 = wm * (BM / 2) + l16;
    const int br0 = wn * (BN / 4) + l16;

    u16* sA0 = sAll;        u16* sB0 = sAll + BM * 64;
    u16* sA1 = sAll + TILE; u16* sB1 = sAll + TILE + BM * 64;

    // prologue: tile 0 -> buf 0
    stage_tile<BM>(Ab, K, 0, sA0, tid);
    stage_tile<BN>(Bb, K, 0, sB0, tid);

    const int nt = K >> 6;
    for (int t = 0; t < nt; ++t) {
        const u16* cA = (t & 1) ? sA1 : sA0;
        const u16* cB = (t & 1) ? sB1 : sB0;
        if (t + 1 < nt) {
            u16* nA = (t & 1) ? sA0 : sA1;
            u16* nB = (t & 1) ? sB0 : sB1;
            stage_tile<BM>(Ab, K, (t + 1) * 64, nA, tid);
            stage_tile<BN>(Bb, K, (t + 1) * 64, nB, tid);
            waitvm<(BM + BN) / 64>();   // tile t landed; t+1 stays in flight
        } else {
            waitvm<0>();                // tail drain
        }
        block_sync();                    // all waves see tile t
#pragma unroll
        for (int kk = 0; kk < 2; ++kk) {
            const int c = kk * 4 + quad;
            bf16x8 af[MR], bf[NR];
#pragma unroll
            for (int m = 0; m < MR; ++m) {
                int r = ar0 + m * 16;
                af[m] = *(const bf16x8*)&cA[r * 64 + ((c ^ (r & 7)) * 8)];
            }
#pragma unroll
            for (int n = 0; n < NR; ++n) {
                int r = br0 + n * 16;
                bf[n] = *(const bf16x8*)&cB[r * 64 + ((c ^ (r & 7)) * 8)];
            }
            __builtin_amdgcn_s_setprio(1);
#pragma unroll
            for (int m = 0; m < MR; ++m)
#pragma unroll
                for (int n = 0; n < NR; ++n)
                    acc[m][n] = __builtin_amdgcn_mfma_f32_16x16x32_bf16(
                        af[m], bf[n], acc[m][n], 0, 0, 0);
            __builtin_amdgcn_s_setprio(0);
        }
        block_sync();                    // frag reads done -> buf free
    }
}

// ---------------- o-proj GEMM: C = A * B^T, fp32 out (128x256 tile) ---------
// XCD-chunked: 256 blocks, xcd=bid%8 owns a 4(bn) x 8(bm) rectangle.
__global__ __launch_bounds__(512, 2)
void gemm_bt(const u16* __restrict__ A, const u16* __restrict__ B,
             float* __restrict__ C, int M, int N, int K) {
    __shared__ u16 sAll[2 * (128 + 256) * 64];
    const int tid = threadIdx.x;
    const int wave = tid >> 6, lane = tid & 63;
    const int quad = lane >> 4, l16 = lane & 15;
    const int wm = wave >> 2, wn = wave & 3;
    const int bid = blockIdx.x;
    const int xcd = bid & 7, r2 = bid >> 3;          // r2 in [0,32)
    const int bni = (xcd & 1) * 4 + (r2 & 3);        // [0,8)
    const int bmi = (xcd >> 1) * 8 + (r2 >> 2);      // [0,32)
    const size_t bm = (size_t)bmi * 128, bn = (size_t)bni * 256;
    f32x4 acc[4][4] = {};
    gemm_pipeline<128, 256>(A + bm * K, B + bn * K, K, sAll, acc, tid);
#pragma unroll
    for (int m = 0; m < 4; ++m)
#pragma unroll
        for (int n = 0; n < 4; ++n)
#pragma unroll
            for (int r = 0; r < 4; ++r)
                C[(bm + wm * 64 + m * 16 + quad * 4 + r) * (size_t)N +
                  bn + wn * 64 + n * 16 + l16] = acc[m][n][r];
}

// ---------------- fused QKV GEMM (256x256): RMSNorm+RoPE (q,k) / transpose (v)
// N-tile bx: 0..7 = Q heads (2bx,2bx+1), 8..9 = K heads, 10..11 = V heads.
// XCD-chunked: 192 blocks, xcd owns a 6(bx) x 4(by) rectangle.
__global__ __launch_bounds__(512, 2)
void gemm_qkv(const u16* __restrict__ xb, const u16* __restrict__ wq,
              const float* __restrict__ qw, const float* __restrict__ kw,
              const float* __restrict__ fcos, const float* __restrict__ fsin,
              u16* __restrict__ qb, u16* __restrict__ kb, u16* __restrict__ vt) {
    __shared__ u16 sAll[2 * (256 + 256) * 64];
    const int tid = threadIdx.x;
    const int wave = tid >> 6, lane = tid & 63;
    const int quad = lane >> 4, l16 = lane & 15;
    const int wm = wave >> 2, wn = wave & 3;
    const int bid = blockIdx.x;
    const int xcd = bid & 7, r2 = bid >> 3;          // r2 in [0,24)
    const int bx = (xcd & 1) * 6 + r2 % 6;           // [0,12)
    const int by = (xcd >> 1) * 4 + r2 / 6;          // [0,16)
    f32x4 acc[8][4] = {};
    gemm_pipeline<256, 256>(xb + (size_t)by * 256 * 2048,
                            wq + (size_t)bx * 256 * 2048, 2048, sAll, acc, tid);

    const int b = by >> 3;                       // batch
    const int sb = (by & 7) * 256 + wm * 128;    // seq pos base (+m*16+quad*4+r)
    const int headh = wn >> 1;                   // which head of the 2 in tile
    const int dcol0 = (wn & 1) * 64;             // dim base within head (+n*16+l16)

    if (bx >= 10) {
        // V: bf16 transpose store, 4 consecutive s per bf16x4
        const int kvh = (bx - 10) * 2 + headh;
        u16* base = vt + (size_t)(b * 4 + kvh) * 128 * 2048;
#pragma unroll
        for (int m = 0; m < 8; ++m) {
            int s0 = sb + m * 16 + quad * 4;
#pragma unroll
            for (int n = 0; n < 4; ++n) {
                int d = dcol0 + n * 16 + l16;
                bf16x4 pv;
#pragma unroll
                for (int r = 0; r < 4; ++r) pv[r] = (__bf16)acc[m][n][r];
                *(bf16x4*)(base + (size_t)d * 2048 + s0) = pv;
            }
        }
        return;
    }

    // Q/K: RMSNorm + RoPE
    float* red = (float*)sAll;   // [parity(2)][headh(2)][row(256)] partial ssq
    float ssq[8][4];
#pragma unroll
    for (int m = 0; m < 8; ++m)
#pragma unroll
        for (int r = 0; r < 4; ++r) {
            float t = 0.f;
#pragma unroll
            for (int n = 0; n < 4; ++n) t += acc[m][n][r] * acc[m][n][r];
#pragma unroll
            for (int off = 1; off <= 8; off <<= 1) t += __shfl_xor(t, off);
            ssq[m][r] = t;
        }
    if (l16 == 0)
#pragma unroll
        for (int m = 0; m < 8; ++m)
#pragma unroll
            for (int r = 0; r < 4; ++r)
                red[((wn & 1) * 2 + headh) * 256 + wm * 128 + m * 16 + quad * 4 + r] =
                    ssq[m][r];
    __syncthreads();

    const bool isQ = bx < 8;
    const float qscl = isQ ? 0.08838834764831845f * 1.4426950408889634f : 1.0f;
    const float* wp = isQ ? qw : kw;
    float wcol[4];
#pragma unroll
    for (int n = 0; n < 4; ++n) wcol[n] = wp[dcol0 + n * 16 + l16];
    u16* dstbase = isQ ? qb + (size_t)(b * 16 + bx * 2 + headh) * 2048 * 128
                       : kb + (size_t)(b * 4 + (bx - 8) * 2 + headh) * 2048 * 128;
    const float sgn = (l16 & 1) ? 1.f : -1.f;

#pragma unroll
    for (int m = 0; m < 8; ++m) {
#pragma unroll
        for (int r = 0; r < 4; ++r) {
            int rowl = wm * 128 + m * 16 + quad * 4 + r;
            float var = (red[(0 + headh) * 256 + rowl] +
                         red[(2 + headh) * 256 + rowl]) * (1.0f / 128.0f);
            float rms = rsqrtf(var + 1.1920928955078125e-07f) * qscl;
            int s = sb + m * 16 + quad * 4 + r;
            const float* fc = fcos + (size_t)s * 128 + dcol0;
            const float* fn = fsin + (size_t)s * 128 + dcol0;
            u16* drow = dstbase + (size_t)s * 128 + dcol0;
#pragma unroll
            for (int n = 0; n < 4; ++n) {
                float y = acc[m][n][r] * rms * wcol[n];
                float yp = __shfl_xor(y, 1);
                float o = y * fc[n * 16 + l16] + sgn * yp * fn[n * 16 + l16];
                drow[n * 16 + l16] = f2bf(o);
            }
        }
    }
}

// ---------------- flash attention v3: 32x32 mfma, reg-P, dbuf, swizzled LDS --
// XCD swizzle: 512 blocks, xcd k owns bh in [4k,4k+4) -> its K/V working set
// is exactly 4 MiB = one XCD L2. Each head's K/V fetched from HBM once.
#define KBUF(c) ((c) * 8192)
#define VBUF(c) (16384 + (c) * 8192)
__global__ __launch_bounds__(256, 2)
void flash_attn(const u16* __restrict__ qb, const u16* __restrict__ kb,
                const u16* __restrict__ vt, u16* __restrict__ ab) {
    __shared__ u16 smem[32768];
    __shared__ float Llds[128];

    const int tid = threadIdx.x;
    const int wave = tid >> 6, lane = tid & 63;
    const int hf = lane >> 5, c32 = lane & 31;
    const int bid = blockIdx.x;
    const int swz = (bid & 7) * 64 + (bid >> 3);
    const int qt = swz & 15, bh = swz >> 4;
    const int hh = bh & 15, bb = bh >> 4;
    const int kh = hh >> 2;

    const u16* Qbase = qb + (size_t)(bb * 16 + hh) * 2048 * 128;
    const u16* Kbase = kb + (size_t)(bb * 4 + kh) * 2048 * 128;
    const u16* Vbase = vt + (size_t)(bb * 4 + kh) * 128 * 2048;

    bf16x8 aq[8];
#pragma unroll
    for (int kq = 0; kq < 8; ++kq)
        aq[kq] = *(const bf16x8*)(Qbase +
            (size_t)(qt * 128 + wave * 32 + c32) * 128 + kq * 16 + hf * 8);

    f32x16 O[4] = {};
    float lacc = 0.f;

    const int st_key = tid >> 4, st_c16 = tid & 15;
    const int st_d = tid >> 3, st_c8 = tid & 7;

    u16x8 kreg[4], vreg[4];
#pragma unroll
    for (int it = 0; it < 4; ++it) {
        int key = st_key + it * 16, d = st_d + it * 32;
        kreg[it] = *(const u16x8*)(Kbase + (size_t)key * 128 + st_c16 * 8);
        vreg[it] = *(const u16x8*)(Vbase + (size_t)d * 2048 + st_c8 * 8);
    }
#pragma unroll
    for (int it = 0; it < 4; ++it) {
        int key = st_key + it * 16, d = st_d + it * 32;
        *(u16x8*)&smem[KBUF(0) + key * 128 + ((st_c16 ^ (key & 7)) * 8)] = kreg[it];
        *(u16x8*)&smem[VBUF(0) + d * 64 + ((st_c8 ^ (d & 7)) * 8)] = vreg[it];
    }
    __syncthreads();

    for (int kt = 0; kt < 32; ++kt) {
        const int cur = kt & 1, nxt = cur ^ 1;
        if (kt < 31) {
            const int key0n = (kt + 1) * 64;
#pragma unroll
            for (int it = 0; it < 4; ++it) {
                int key = st_key + it * 16, d = st_d + it * 32;
                kreg[it] = *(const u16x8*)(Kbase + (size_t)(key0n + key) * 128 + st_c16 * 8);
                vreg[it] = *(const u16x8*)(Vbase + (size_t)d * 2048 + key0n + st_c8 * 8);
            }
        }

        f32x16 sc[2] = {};
        __builtin_amdgcn_s_setprio(1);
#pragma unroll
        for (int kq = 0; kq < 8; ++kq) {
#pragma unroll
            for (int mt = 0; mt < 2; ++mt) {
                bf16x8 kf = *(const bf16x8*)&smem[KBUF(cur) + (mt * 32 + c32) * 128 +
                                                 (((kq * 2 + hf) ^ (c32 & 7)) * 8)];
                sc[mt] = __builtin_amdgcn_mfma_f32_32x32x16_bf16(kf, aq[kq], sc[mt], 0, 0, 0);
            }
        }
        __builtin_amdgcn_s_setprio(0);

        int pdw[2][8];
#pragma unroll
        for (int mt = 0; mt < 2; ++mt) {
            float p[16];
#pragma unroll
            for (int r = 0; r < 16; ++r) {
                p[r] = __builtin_amdgcn_exp2f(sc[mt][r]);
                lacc += p[r];
            }
#pragma unroll
            for (int i = 0; i < 8; ++i) pdw[mt][i] = (int)pkbf2(p[2 * i], p[2 * i + 1]);
        }

        if (kt < 31) {
#pragma unroll
            for (int it = 0; it < 4; ++it) {
                int key = st_key + it * 16, d = st_d + it * 32;
                *(u16x8*)&smem[KBUF(nxt) + key * 128 + ((st_c16 ^ (key & 7)) * 8)] = kreg[it];
                *(u16x8*)&smem[VBUF(nxt) + d * 64 + ((st_c8 ^ (d & 7)) * 8)] = vreg[it];
            }
        }

#pragma unroll
        for (int kc = 0; kc < 4; ++kc) {
            const int mt = kc >> 1, L = kc & 1;
            int s0 = hf ? pdw[mt][4 * L + 0] : pdw[mt][4 * L + 2];
            int s1 = hf ? pdw[mt][4 * L + 1] : pdw[mt][4 * L + 3];
            int r0 = __shfl_xor(s0, 32);
            int r1 = __shfl_xor(s1, 32);
            union { int i[4]; bf16x8 v; } u;
            u.i[0] = hf ? r0 : pdw[mt][4 * L + 0];
            u.i[1] = hf ? r1 : pdw[mt][4 * L + 1];
            u.i[2] = hf ? pdw[mt][4 * L + 2] : r0;
            u.i[3] = hf ? pdw[mt][4 * L + 3] : r1;
            __builtin_amdgcn_s_setprio(1);
#pragma unroll
            for (int dt = 0; dt < 4; ++dt) {
                bf16x8 vf = *(const bf16x8*)&smem[VBUF(cur) + (dt * 32 + c32) * 64 +
                                                 (((kc * 2 + hf) ^ (c32 & 7)) * 8)];
                O[dt] = __builtin_amdgcn_mfma_f32_32x32x16_bf16(u.v, vf, O[dt], 0, 0, 0);
            }
            __builtin_amdgcn_s_setprio(0);
        }
        __syncthreads();
    }

    float l = lacc + __shfl_xor(lacc, 32);
    if (hf == 0) Llds[wave * 32 + c32] = l;

    float inv[16];
#pragma unroll
    for (int r = 0; r < 16; ++r)
        inv[r] = __builtin_amdgcn_rcpf(Llds[wave * 32 + (r & 3) + 8 * (r >> 2) + 4 * hf]);

    u16* scr = &smem[wave * 32 * 136];
#pragma unroll
    for (int dt = 0; dt < 4; ++dt)
#pragma unroll
        for (int r = 0; r < 16; ++r) {
            int q_r = (r & 3) + 8 * (r >> 2) + 4 * hf;
            scr[q_r * 136 + dt * 32 + c32] = f2bf(O[dt][r] * inv[r]);
        }
#pragma unroll
    for (int it = 0; it < 8; ++it) {
        int f = it * 64 + lane;
        int row = f >> 4, c = f & 15;
        u16x8 v = *(const u16x8*)&scr[row * 136 + c * 8];
        int qg = qt * 128 + wave * 32 + row;
        *(u16x8*)(ab + ((size_t)(bb * 2048 + qg)) * 2048 + hh * 128 + c * 8) = v;
    }
}

// ---------------- host launch ----------------
extern "C" void kernel_launch(void* const* d_in, const int* in_sizes, int n_in,
                              void* d_out, int out_size, void* d_ws, size_t ws_size,
                              hipStream_t stream) {
    const float* x    = (const float*)d_in[0];
    const float* wqkv = (const float*)d_in[1];
    const float* wo   = (const float*)d_in[2];
    const float* qw   = (const float*)d_in[3];
    const float* kw   = (const float*)d_in[4];
    const float* fc   = (const float*)d_in[5];
    const float* fs   = (const float*)d_in[6];
    float* out = (float*)d_out;
    char* ws = (char*)d_ws;

    u16* xb    = (u16*)(ws + 0);          // 4096x2048 bf16 (16 MB)
    u16* wqkvb = (u16*)(ws + 16777216);   // 3072x2048 bf16 (12 MB)
    u16* wob   = (u16*)(ws + 29360128);   // 2048x2048 bf16 ( 8 MB)
    u16* qb    = (u16*)(ws + 37748736);   // [2,16,2048,128] (16 MB)
    u16* kb    = (u16*)(ws + 54525952);   // [2,4,2048,128]  ( 4 MB)
    u16* vt    = (u16*)(ws + 58720256);   // [2,4,128,2048]  ( 4 MB)
    u16* ab    = (u16*)(ws + 62914560);   // 4096x2048 bf16  (16 MB)

    cvt_bf16<<<8192, 256, 0, stream>>>(x, xb, 2097152);
    cvt_bf16<<<6144, 256, 0, stream>>>(wqkv, wqkvb, 1572864);
    cvt_bf16<<<4096, 256, 0, stream>>>(wo, wob, 1048576);
    gemm_qkv<<<192, 512, 0, stream>>>(xb, wqkvb, qw, kw, fc, fs, qb, kb, vt);
    flash_attn<<<512, 256, 0, stream>>>(qb, kb, vt, ab);
    gemm_bt<<<256, 512, 0, stream>>>(ab, wob, out, 4096, 2048, 2048);
}

// Round 7
// 305.248 us; speedup vs baseline: 1.1034x; 1.0266x over previous
//
#include <hip/hip_runtime.h>
#include <hip/hip_bf16.h>

typedef unsigned short u16;
typedef __bf16 bf16x8 __attribute__((ext_vector_type(8)));
typedef __bf16 bf16x4 __attribute__((ext_vector_type(4)));
typedef u16 u16x8 __attribute__((ext_vector_type(8)));
typedef float f32x4 __attribute__((ext_vector_type(4)));
typedef float f32x16 __attribute__((ext_vector_type(16)));

__device__ __forceinline__ u16 f2bf(float f) {
    unsigned u = __float_as_uint(f);
    return (u16)((u + 0x7fffu + ((u >> 16) & 1u)) >> 16);
}
__device__ __forceinline__ unsigned pkbf2(float a, float b) {
    __hip_bfloat162 h = __float22bfloat162_rn(make_float2(a, b));
    return *(unsigned*)&h;
}

// async global->LDS, 16B per lane, LDS dest = wave-uniform base + lane*16
__device__ __forceinline__ void gload16(const u16* g, u16* l) {
    __builtin_amdgcn_global_load_lds(
        (const __attribute__((address_space(1))) void*)g,
        (__attribute__((address_space(3))) void*)l, 16, 0, 0);
}

// raw barrier with compile-time scheduling fence (no vmcnt drain!)
__device__ __forceinline__ void block_sync() {
    __builtin_amdgcn_sched_barrier(0);
    __builtin_amdgcn_s_barrier();
    __builtin_amdgcn_sched_barrier(0);
}
template<int N> __device__ __forceinline__ void waitvm() {
    if constexpr (N == 0)      asm volatile("s_waitcnt vmcnt(0)" ::: "memory");
    else if constexpr (N == 6) asm volatile("s_waitcnt vmcnt(6)" ::: "memory");
    else                       asm volatile("s_waitcnt vmcnt(8)" ::: "memory");
}

// ---------------- fp32 -> bf16 convert ----------------
__global__ void cvt_bf16(const float* __restrict__ src, u16* __restrict__ dst, int n4) {
    int i = blockIdx.x * 256 + threadIdx.x;
    if (i >= n4) return;
    float4 v = *(const float4*)(src + (size_t)i * 4);
    uint2 o; o.x = pkbf2(v.x, v.y); o.y = pkbf2(v.z, v.w);
    *(uint2*)(dst + (size_t)i * 4) = o;
}

// ---------------- deep-pipelined GEMM core (256-class tile, BK=64) ----------
template<int ROWS>
__device__ __forceinline__ void stage_tile(const u16* __restrict__ g, int K,
                                           int k0, u16* l, int tid) {
#pragma unroll
    for (int s = 0; s < ROWS / 64; ++s) {
        int row = s * 64 + (tid >> 3);
        int sc = (tid & 7) ^ ((tid >> 3) & 7);
        gload16(g + (size_t)row * K + k0 + sc * 8, l + s * 4096 + tid * 8);
    }
}

template<int BM, int BN>
__device__ __forceinline__ void gemm_pipeline(const u16* __restrict__ Ab,
                                              const u16* __restrict__ Bb, int K,
                                              u16* sAll,
                                              f32x4 (&acc)[BM / 32][BN / 64],
                                              int tid) {
    constexpr int MR = BM / 32, NR = BN / 64;
    constexpr int TILE = (BM + BN) * 64;
    const int lane = tid & 63, wave = tid >> 6;
    const int quad = lane >> 4, l16 = lane & 15;
    const int wm = wave >> 2, wn = wave & 3;
    const int ar0 = wm * (BM / 2) + l16;
    const int br0 = wn * (BN / 4) + l16;

    u16* sA0 = sAll;        u16* sB0 = sAll + BM * 64;
    u16* sA1 = sAll + TILE; u16* sB1 = sAll + TILE + BM * 64;

    stage_tile<BM>(Ab, K, 0, sA0, tid);
    stage_tile<BN>(Bb, K, 0, sB0, tid);

    const int nt = K >> 6;
    for (int t = 0; t < nt; ++t) {
        const u16* cA = (t & 1) ? sA1 : sA0;
        const u16* cB = (t & 1) ? sB1 : sB0;
        if (t + 1 < nt) {
            u16* nA = (t & 1) ? sA0 : sA1;
            u16* nB = (t & 1) ? sB0 : sB1;
            stage_tile<BM>(Ab, K, (t + 1) * 64, nA, tid);
            stage_tile<BN>(Bb, K, (t + 1) * 64, nB, tid);
            waitvm<(BM + BN) / 64>();   // tile t landed; t+1 stays in flight
        } else {
            waitvm<0>();                // tail drain
        }
        block_sync();                    // all waves see tile t
#pragma unroll
        for (int kk = 0; kk < 2; ++kk) {
            const int c = kk * 4 + quad;
            bf16x8 af[MR], bf[NR];
#pragma unroll
            for (int m = 0; m < MR; ++m) {
                int r = ar0 + m * 16;
                af[m] = *(const bf16x8*)&cA[r * 64 + ((c ^ (r & 7)) * 8)];
            }
#pragma unroll
            for (int n = 0; n < NR; ++n) {
                int r = br0 + n * 16;
                bf[n] = *(const bf16x8*)&cB[r * 64 + ((c ^ (r & 7)) * 8)];
            }
            __builtin_amdgcn_s_setprio(1);
#pragma unroll
            for (int m = 0; m < MR; ++m)
#pragma unroll
                for (int n = 0; n < NR; ++n)
                    acc[m][n] = __builtin_amdgcn_mfma_f32_16x16x32_bf16(
                        af[m], bf[n], acc[m][n], 0, 0, 0);
            __builtin_amdgcn_s_setprio(0);
        }
        block_sync();                    // frag reads done -> buf free
    }
}

// ---------------- o-proj GEMM: C = A * B^T, fp32 out (128x256 tile) ---------
__global__ __launch_bounds__(512, 2)
void gemm_bt(const u16* __restrict__ A, const u16* __restrict__ B,
             float* __restrict__ C, int M, int N, int K) {
    __shared__ u16 sAll[2 * (128 + 256) * 64];
    const int tid = threadIdx.x;
    const int wave = tid >> 6, lane = tid & 63;
    const int quad = lane >> 4, l16 = lane & 15;
    const int wm = wave >> 2, wn = wave & 3;
    const int bid = blockIdx.x;
    const int xcd = bid & 7, r2 = bid >> 3;          // r2 in [0,32)
    const int bni = (xcd & 1) * 4 + (r2 & 3);        // [0,8)
    const int bmi = (xcd >> 1) * 8 + (r2 >> 2);      // [0,32)
    const size_t bm = (size_t)bmi * 128, bn = (size_t)bni * 256;
    f32x4 acc[4][4] = {};
    gemm_pipeline<128, 256>(A + bm * K, B + bn * K, K, sAll, acc, tid);
#pragma unroll
    for (int m = 0; m < 4; ++m)
#pragma unroll
        for (int n = 0; n < 4; ++n)
#pragma unroll
            for (int r = 0; r < 4; ++r)
                C[(bm + wm * 64 + m * 16 + quad * 4 + r) * (size_t)N +
                  bn + wn * 64 + n * 16 + l16] = acc[m][n][r];
}

// ---------------- fused QKV GEMM (256x256): RMSNorm+RoPE (q,k) / transpose (v)
// V is stored KEY-PERMUTED: within each 16-seq group, slot = swap(bits2,3) of
// seq. This makes flash PV consume each lane's own QK^T output directly
// (no cross-lane P exchange). sigma is an involution; sum P.V is invariant.
__global__ __launch_bounds__(512, 2)
void gemm_qkv(const u16* __restrict__ xb, const u16* __restrict__ wq,
              const float* __restrict__ qw, const float* __restrict__ kw,
              const float* __restrict__ fcos, const float* __restrict__ fsin,
              u16* __restrict__ qb, u16* __restrict__ kb, u16* __restrict__ vt) {
    __shared__ u16 sAll[2 * (256 + 256) * 64];
    const int tid = threadIdx.x;
    const int wave = tid >> 6, lane = tid & 63;
    const int quad = lane >> 4, l16 = lane & 15;
    const int wm = wave >> 2, wn = wave & 3;
    const int bid = blockIdx.x;
    const int xcd = bid & 7, r2 = bid >> 3;          // r2 in [0,24)
    const int bx = (xcd & 1) * 6 + r2 % 6;           // [0,12)
    const int by = (xcd >> 1) * 4 + r2 / 6;          // [0,16)
    f32x4 acc[8][4] = {};
    gemm_pipeline<256, 256>(xb + (size_t)by * 256 * 2048,
                            wq + (size_t)bx * 256 * 2048, 2048, sAll, acc, tid);

    const int b = by >> 3;                       // batch
    const int sb = (by & 7) * 256 + wm * 128;    // seq pos base (+m*16+quad*4+r)
    const int headh = wn >> 1;                   // which head of the 2 in tile
    const int dcol0 = (wn & 1) * 64;             // dim base within head (+n*16+l16)

    if (bx >= 10) {
        // V: bf16 transpose store, sigma-permuted quad (1<->2)
        const int qp = ((quad & 1) << 1) | (quad >> 1);
        const int kvh = (bx - 10) * 2 + headh;
        u16* base = vt + (size_t)(b * 4 + kvh) * 128 * 2048;
#pragma unroll
        for (int m = 0; m < 8; ++m) {
            int s0 = sb + m * 16 + qp * 4;
#pragma unroll
            for (int n = 0; n < 4; ++n) {
                int d = dcol0 + n * 16 + l16;
                bf16x4 pv;
#pragma unroll
                for (int r = 0; r < 4; ++r) pv[r] = (__bf16)acc[m][n][r];
                *(bf16x4*)(base + (size_t)d * 2048 + s0) = pv;
            }
        }
        return;
    }

    // Q/K: RMSNorm + RoPE
    float* red = (float*)sAll;   // [parity(2)][headh(2)][row(256)] partial ssq
    float ssq[8][4];
#pragma unroll
    for (int m = 0; m < 8; ++m)
#pragma unroll
        for (int r = 0; r < 4; ++r) {
            float t = 0.f;
#pragma unroll
            for (int n = 0; n < 4; ++n) t += acc[m][n][r] * acc[m][n][r];
#pragma unroll
            for (int off = 1; off <= 8; off <<= 1) t += __shfl_xor(t, off);
            ssq[m][r] = t;
        }
    if (l16 == 0)
#pragma unroll
        for (int m = 0; m < 8; ++m)
#pragma unroll
            for (int r = 0; r < 4; ++r)
                red[((wn & 1) * 2 + headh) * 256 + wm * 128 + m * 16 + quad * 4 + r] =
                    ssq[m][r];
    __syncthreads();

    const bool isQ = bx < 8;
    const float qscl = isQ ? 0.08838834764831845f * 1.4426950408889634f : 1.0f;
    const float* wp = isQ ? qw : kw;
    float wcol[4];
#pragma unroll
    for (int n = 0; n < 4; ++n) wcol[n] = wp[dcol0 + n * 16 + l16];
    u16* dstbase = isQ ? qb + (size_t)(b * 16 + bx * 2 + headh) * 2048 * 128
                       : kb + (size_t)(b * 4 + (bx - 8) * 2 + headh) * 2048 * 128;
    const float sgn = (l16 & 1) ? 1.f : -1.f;

#pragma unroll
    for (int m = 0; m < 8; ++m) {
#pragma unroll
        for (int r = 0; r < 4; ++r) {
            int rowl = wm * 128 + m * 16 + quad * 4 + r;
            float var = (red[(0 + headh) * 256 + rowl] +
                         red[(2 + headh) * 256 + rowl]) * (1.0f / 128.0f);
            float rms = rsqrtf(var + 1.1920928955078125e-07f) * qscl;
            int s = sb + m * 16 + quad * 4 + r;
            const float* fc = fcos + (size_t)s * 128 + dcol0;
            const float* fn = fsin + (size_t)s * 128 + dcol0;
            u16* drow = dstbase + (size_t)s * 128 + dcol0;
#pragma unroll
            for (int n = 0; n < 4; ++n) {
                float y = acc[m][n][r] * rms * wcol[n];
                float yp = __shfl_xor(y, 1);
                float o = y * fc[n * 16 + l16] + sgn * yp * fn[n * 16 + l16];
                drow[n * 16 + l16] = f2bf(o);
            }
        }
    }
}

// ---------------- flash attention v4: gload_lds staging, zero-shuffle PV ----
// K/V staged by global_load_lds (pre-swizzled source, linear LDS dest),
// counted vmcnt(8) keeps next tile in flight across the barrier. V is
// key-permuted (sigma) at the producer, so each lane's PV A-fragment is its
// own pdw words: no cross-lane exchange (the old 8.45M-conflict shfl path).
#define KBUF(c) ((c) * 8192)
#define VBUF(c) (16384 + (c) * 8192)
__global__ __launch_bounds__(256, 2)
void flash_attn(const u16* __restrict__ qb, const u16* __restrict__ kb,
                const u16* __restrict__ vt, u16* __restrict__ ab) {
    __shared__ u16 smem[32768];
    __shared__ float Llds[128];

    const int tid = threadIdx.x;
    const int wave = tid >> 6, lane = tid & 63;
    const int hf = lane >> 5, c32 = lane & 31;
    const int bid = blockIdx.x;
    const int swz = (bid & 7) * 64 + (bid >> 3);
    const int qt = swz & 15, bh = swz >> 4;
    const int hh = bh & 15, bb = bh >> 4;
    const int kh = hh >> 2;

    const u16* Qbase = qb + (size_t)(bb * 16 + hh) * 2048 * 128;
    const u16* Kbase = kb + (size_t)(bb * 4 + kh) * 2048 * 128;
    const u16* Vbase = vt + (size_t)(bb * 4 + kh) * 128 * 2048;

    bf16x8 aq[8];
#pragma unroll
    for (int kq = 0; kq < 8; ++kq)
        aq[kq] = *(const bf16x8*)(Qbase +
            (size_t)(qt * 128 + wave * 32 + c32) * 128 + kq * 16 + hf * 8);

    f32x16 O[4] = {};
    float lacc = 0.f;

    // staging geometry: K tile [64 key][128 d], V tile [128 d][64 key].
    // LDS chunk pos p holds source chunk p ^ (row&7)  (read XOR matches).
    const int krow = tid >> 4;                         // 0..15 within 16-row seg
    const u16* kg = Kbase + (size_t)krow * 128 + (((tid & 15) ^ (krow & 7)) * 8);
    const int vrow = tid >> 3;                         // 0..31 within 32-row seg
    const u16* vg = Vbase + (size_t)vrow * 2048 + (((tid & 7) ^ (vrow & 7)) * 8);

    auto stage = [&](int buf, int key0) {
#pragma unroll
        for (int s = 0; s < 4; ++s) {
            gload16(kg + key0 * 128 + s * 2048, &smem[KBUF(buf) + s * 2048 + tid * 8]);
            gload16(vg + (size_t)s * 65536 + key0, &smem[VBUF(buf) + s * 2048 + tid * 8]);
        }
    };

    stage(0, 0);

    for (int kt = 0; kt < 32; ++kt) {
        const int cur = kt & 1, nxt = cur ^ 1;
        if (kt < 31) {
            stage(nxt, (kt + 1) * 64);
            waitvm<8>();               // tile kt landed; kt+1 stays in flight
        } else {
            waitvm<0>();
        }
        block_sync();

        f32x16 sc[2] = {};
        __builtin_amdgcn_s_setprio(1);
#pragma unroll
        for (int kq = 0; kq < 8; ++kq) {
#pragma unroll
            for (int mt = 0; mt < 2; ++mt) {
                bf16x8 kf = *(const bf16x8*)&smem[KBUF(cur) + (mt * 32 + c32) * 128 +
                                                 (((kq * 2 + hf) ^ (c32 & 7)) * 8)];
                sc[mt] = __builtin_amdgcn_mfma_f32_32x32x16_bf16(kf, aq[kq], sc[mt], 0, 0, 0);
            }
        }
        __builtin_amdgcn_s_setprio(0);

        int pdw[2][8];
#pragma unroll
        for (int mt = 0; mt < 2; ++mt) {
            float p[16];
#pragma unroll
            for (int r = 0; r < 16; ++r) {
                p[r] = __builtin_amdgcn_exp2f(sc[mt][r]);
                lacc += p[r];
            }
#pragma unroll
            for (int i = 0; i < 8; ++i) pdw[mt][i] = (int)pkbf2(p[2 * i], p[2 * i + 1]);
        }

        __builtin_amdgcn_s_setprio(1);
#pragma unroll
        for (int kc = 0; kc < 4; ++kc) {
            const int mt = kc >> 1, L = kc & 1;
            union { int i[4]; bf16x8 v; } u;
            u.i[0] = pdw[mt][4 * L + 0];
            u.i[1] = pdw[mt][4 * L + 1];
            u.i[2] = pdw[mt][4 * L + 2];
            u.i[3] = pdw[mt][4 * L + 3];
#pragma unroll
            for (int dt = 0; dt < 4; ++dt) {
                bf16x8 vf = *(const bf16x8*)&smem[VBUF(cur) + (dt * 32 + c32) * 64 +
                                                 (((kc * 2 + hf) ^ (c32 & 7)) * 8)];
                O[dt] = __builtin_amdgcn_mfma_f32_32x32x16_bf16(u.v, vf, O[dt], 0, 0, 0);
            }
        }
        __builtin_amdgcn_s_setprio(0);
        block_sync();                  // reads of cur done -> next iter may DMA
    }

    float l = lacc + __shfl_xor(lacc, 32);
    if (hf == 0) Llds[wave * 32 + c32] = l;

    float inv[16];
#pragma unroll
    for (int r = 0; r < 16; ++r)
        inv[r] = __builtin_amdgcn_rcpf(Llds[wave * 32 + (r & 3) + 8 * (r >> 2) + 4 * hf]);

    u16* scr = &smem[wave * 32 * 136];
#pragma unroll
    for (int dt = 0; dt < 4; ++dt)
#pragma unroll
        for (int r = 0; r < 16; ++r) {
            int q_r = (r & 3) + 8 * (r >> 2) + 4 * hf;
            scr[q_r * 136 + dt * 32 + c32] = f2bf(O[dt][r] * inv[r]);
        }
#pragma unroll
    for (int it = 0; it < 8; ++it) {
        int f = it * 64 + lane;
        int row = f >> 4, c = f & 15;
        u16x8 v = *(const u16x8*)&scr[row * 136 + c * 8];
        int qg = qt * 128 + wave * 32 + row;
        *(u16x8*)(ab + ((size_t)(bb * 2048 + qg)) * 2048 + hh * 128 + c * 8) = v;
    }
}

// ---------------- host launch ----------------
extern "C" void kernel_launch(void* const* d_in, const int* in_sizes, int n_in,
                              void* d_out, int out_size, void* d_ws, size_t ws_size,
                              hipStream_t stream) {
    const float* x    = (const float*)d_in[0];
    const float* wqkv = (const float*)d_in[1];
    const float* wo   = (const float*)d_in[2];
    const float* qw   = (const float*)d_in[3];
    const float* kw   = (const float*)d_in[4];
    const float* fc   = (const float*)d_in[5];
    const float* fs   = (const float*)d_in[6];
    float* out = (float*)d_out;
    char* ws = (char*)d_ws;

    u16* xb    = (u16*)(ws + 0);          // 4096x2048 bf16 (16 MB)
    u16* wqkvb = (u16*)(ws + 16777216);   // 3072x2048 bf16 (12 MB)
    u16* wob   = (u16*)(ws + 29360128);   // 2048x2048 bf16 ( 8 MB)
    u16* qb    = (u16*)(ws + 37748736);   // [2,16,2048,128] (16 MB)
    u16* kb    = (u16*)(ws + 54525952);   // [2,4,2048,128]  ( 4 MB)
    u16* vt    = (u16*)(ws + 58720256);   // [2,4,128,2048]  ( 4 MB, key-permuted)
    u16* ab    = (u16*)(ws + 62914560);   // 4096x2048 bf16  (16 MB)

    cvt_bf16<<<8192, 256, 0, stream>>>(x, xb, 2097152);
    cvt_bf16<<<6144, 256, 0, stream>>>(wqkv, wqkvb, 1572864);
    cvt_bf16<<<4096, 256, 0, stream>>>(wo, wob, 1048576);
    gemm_qkv<<<192, 512, 0, stream>>>(xb, wqkvb, qw, kw, fc, fs, qb, kb, vt);
    flash_attn<<<512, 256, 0, stream>>>(qb, kb, vt, ab);
    gemm_bt<<<256, 512, 0, stream>>>(ab, wob, out, 4096, 2048, 2048);
}

// Round 9
// 300.071 us; speedup vs baseline: 1.1224x; 1.0173x over previous
//
#include <hip/hip_runtime.h>
#include <hip/hip_bf16.h>

typedef unsigned short u16;
typedef __bf16 bf16x8 __attribute__((ext_vector_type(8)));
typedef __bf16 bf16x4 __attribute__((ext_vector_type(4)));
typedef u16 u16x8 __attribute__((ext_vector_type(8)));
typedef float f32x4 __attribute__((ext_vector_type(4)));
typedef float f32x16 __attribute__((ext_vector_type(16)));

__device__ __forceinline__ u16 f2bf(float f) {
    unsigned u = __float_as_uint(f);
    return (u16)((u + 0x7fffu + ((u >> 16) & 1u)) >> 16);
}
__device__ __forceinline__ unsigned pkbf2(float a, float b) {
    __hip_bfloat162 h = __float22bfloat162_rn(make_float2(a, b));
    return *(unsigned*)&h;
}

// async global->LDS, 16B per lane, LDS dest = wave-uniform base + lane*16
__device__ __forceinline__ void gload16(const u16* g, u16* l) {
    __builtin_amdgcn_global_load_lds(
        (const __attribute__((address_space(1))) void*)g,
        (__attribute__((address_space(3))) void*)l, 16, 0, 0);
}

// raw barrier with compile-time scheduling fence (no vmcnt drain!)
__device__ __forceinline__ void block_sync() {
    __builtin_amdgcn_sched_barrier(0);
    __builtin_amdgcn_s_barrier();
    __builtin_amdgcn_sched_barrier(0);
}
template<int N> __device__ __forceinline__ void waitvm() {
    if constexpr (N == 0)      asm volatile("s_waitcnt vmcnt(0)" ::: "memory");
    else if constexpr (N == 4) asm volatile("s_waitcnt vmcnt(4)" ::: "memory");
    else if constexpr (N == 6) asm volatile("s_waitcnt vmcnt(6)" ::: "memory");
    else                       asm volatile("s_waitcnt vmcnt(8)" ::: "memory");
}

// ---------------- fp32 -> bf16 convert (x, wqkv, wo fused in one launch) ----
#define CVT_N1 2097152
#define CVT_N2 3670016
#define CVT_TOT 4718592
__global__ void cvt_all(const float* __restrict__ x, const float* __restrict__ wqkv,
                        const float* __restrict__ wo, u16* __restrict__ xb,
                        u16* __restrict__ wqkvb, u16* __restrict__ wob) {
    for (int i = blockIdx.x * 256 + threadIdx.x; i < CVT_TOT; i += 4608 * 256) {
        const float* s; u16* d; int j;
        if (i < CVT_N1)      { s = x;    d = xb;    j = i; }
        else if (i < CVT_N2) { s = wqkv; d = wqkvb; j = i - CVT_N1; }
        else                 { s = wo;   d = wob;   j = i - CVT_N2; }
        float4 v = *(const float4*)(s + (size_t)j * 4);
        uint2 o; o.x = pkbf2(v.x, v.y); o.y = pkbf2(v.z, v.w);
        *(uint2*)(d + (size_t)j * 4) = o;
    }
}

// ---------------- deep-pipelined GEMM core (256-class tile, BK=64) ----------
template<int ROWS>
__device__ __forceinline__ void stage_tile(const u16* __restrict__ g, int K,
                                           int k0, u16* l, int tid) {
#pragma unroll
    for (int s = 0; s < ROWS / 64; ++s) {
        int row = s * 64 + (tid >> 3);
        int sc = (tid & 7) ^ ((tid >> 3) & 7);
        gload16(g + (size_t)row * K + k0 + sc * 8, l + s * 4096 + tid * 8);
    }
}

template<int BM, int BN>
__device__ __forceinline__ void gemm_pipeline(const u16* __restrict__ Ab,
                                              const u16* __restrict__ Bb, int K,
                                              u16* sAll,
                                              f32x4 (&acc)[BM / 32][BN / 64],
                                              int tid) {
    constexpr int MR = BM / 32, NR = BN / 64;
    constexpr int TILE = (BM + BN) * 64;
    const int lane = tid & 63, wave = tid >> 6;
    const int quad = lane >> 4, l16 = lane & 15;
    const int wm = wave >> 2, wn = wave & 3;
    const int ar0 = wm * (BM / 2) + l16;
    const int br0 = wn * (BN / 4) + l16;

    u16* sA0 = sAll;        u16* sB0 = sAll + BM * 64;
    u16* sA1 = sAll + TILE; u16* sB1 = sAll + TILE + BM * 64;

    stage_tile<BM>(Ab, K, 0, sA0, tid);
    stage_tile<BN>(Bb, K, 0, sB0, tid);

    const int nt = K >> 6;
    for (int t = 0; t < nt; ++t) {
        const u16* cA = (t & 1) ? sA1 : sA0;
        const u16* cB = (t & 1) ? sB1 : sB0;
        if (t + 1 < nt) {
            u16* nA = (t & 1) ? sA0 : sA1;
            u16* nB = (t & 1) ? sB0 : sB1;
            stage_tile<BM>(Ab, K, (t + 1) * 64, nA, tid);
            stage_tile<BN>(Bb, K, (t + 1) * 64, nB, tid);
            waitvm<(BM + BN) / 64>();   // tile t landed; t+1 stays in flight
        } else {
            waitvm<0>();                // tail drain
        }
        block_sync();                    // all waves see tile t
#pragma unroll
        for (int kk = 0; kk < 2; ++kk) {
            const int c = kk * 4 + quad;
            bf16x8 af[MR], bf[NR];
#pragma unroll
            for (int m = 0; m < MR; ++m) {
                int r = ar0 + m * 16;
                af[m] = *(const bf16x8*)&cA[r * 64 + ((c ^ (r & 7)) * 8)];
            }
#pragma unroll
            for (int n = 0; n < NR; ++n) {
                int r = br0 + n * 16;
                bf[n] = *(const bf16x8*)&cB[r * 64 + ((c ^ (r & 7)) * 8)];
            }
            __builtin_amdgcn_s_setprio(1);
#pragma unroll
            for (int m = 0; m < MR; ++m)
#pragma unroll
                for (int n = 0; n < NR; ++n)
                    acc[m][n] = __builtin_amdgcn_mfma_f32_16x16x32_bf16(
                        af[m], bf[n], acc[m][n], 0, 0, 0);
            __builtin_amdgcn_s_setprio(0);
        }
        block_sync();                    // frag reads done -> buf free
    }
}

// ---------------- o-proj GEMM: C = A * B^T, fp32 out (128x256 tile) ---------
__global__ __launch_bounds__(512, 2)
void gemm_bt(const u16* __restrict__ A, const u16* __restrict__ B,
             float* __restrict__ C, int M, int N, int K) {
    __shared__ u16 sAll[2 * (128 + 256) * 64];
    const int tid = threadIdx.x;
    const int wave = tid >> 6, lane = tid & 63;
    const int quad = lane >> 4, l16 = lane & 15;
    const int wm = wave >> 2, wn = wave & 3;
    const int bid = blockIdx.x;
    const int xcd = bid & 7, r2 = bid >> 3;          // r2 in [0,32)
    const int bni = (xcd & 1) * 4 + (r2 & 3);        // [0,8)
    const int bmi = (xcd >> 1) * 8 + (r2 >> 2);      // [0,32)
    const size_t bm = (size_t)bmi * 128, bn = (size_t)bni * 256;
    f32x4 acc[4][4] = {};
    gemm_pipeline<128, 256>(A + bm * K, B + bn * K, K, sAll, acc, tid);
#pragma unroll
    for (int m = 0; m < 4; ++m)
#pragma unroll
        for (int n = 0; n < 4; ++n)
#pragma unroll
            for (int r = 0; r < 4; ++r)
                C[(bm + wm * 64 + m * 16 + quad * 4 + r) * (size_t)N +
                  bn + wn * 64 + n * 16 + l16] = acc[m][n][r];
}

// ---------------- fused QKV GEMM (256x256): RMSNorm+RoPE (q,k) / transpose (v)
// V is stored KEY-PERMUTED: within each 16-seq group, slot = swap(bits2,3) of
// seq, so flash PV consumes each lane's own QK^T output (no P exchange).
__global__ __launch_bounds__(512, 2)
void gemm_qkv(const u16* __restrict__ xb, const u16* __restrict__ wq,
              const float* __restrict__ qw, const float* __restrict__ kw,
              const float* __restrict__ fcos, const float* __restrict__ fsin,
              u16* __restrict__ qb, u16* __restrict__ kb, u16* __restrict__ vt) {
    __shared__ u16 sAll[2 * (256 + 256) * 64];
    const int tid = threadIdx.x;
    const int wave = tid >> 6, lane = tid & 63;
    const int quad = lane >> 4, l16 = lane & 15;
    const int wm = wave >> 2, wn = wave & 3;
    const int bid = blockIdx.x;
    const int xcd = bid & 7, r2 = bid >> 3;          // r2 in [0,24)
    const int bx = (xcd & 1) * 6 + r2 % 6;           // [0,12)
    const int by = (xcd >> 1) * 4 + r2 / 6;          // [0,16)
    f32x4 acc[8][4] = {};
    gemm_pipeline<256, 256>(xb + (size_t)by * 256 * 2048,
                            wq + (size_t)bx * 256 * 2048, 2048, sAll, acc, tid);

    const int b = by >> 3;                       // batch
    const int sb = (by & 7) * 256 + wm * 128;    // seq pos base (+m*16+quad*4+r)
    const int headh = wn >> 1;                   // which head of the 2 in tile
    const int dcol0 = (wn & 1) * 64;             // dim base within head (+n*16+l16)

    if (bx >= 10) {
        // V: bf16 transpose store, sigma-permuted quad (1<->2)
        const int qp = ((quad & 1) << 1) | (quad >> 1);
        const int kvh = (bx - 10) * 2 + headh;
        u16* base = vt + (size_t)(b * 4 + kvh) * 128 * 2048;
#pragma unroll
        for (int m = 0; m < 8; ++m) {
            int s0 = sb + m * 16 + qp * 4;
#pragma unroll
            for (int n = 0; n < 4; ++n) {
                int d = dcol0 + n * 16 + l16;
                bf16x4 pv;
#pragma unroll
                for (int r = 0; r < 4; ++r) pv[r] = (__bf16)acc[m][n][r];
                *(bf16x4*)(base + (size_t)d * 2048 + s0) = pv;
            }
        }
        return;
    }

    // Q/K: RMSNorm + RoPE
    float* red = (float*)sAll;   // [parity(2)][headh(2)][row(256)] partial ssq
    float ssq[8][4];
#pragma unroll
    for (int m = 0; m < 8; ++m)
#pragma unroll
        for (int r = 0; r < 4; ++r) {
            float t = 0.f;
#pragma unroll
            for (int n = 0; n < 4; ++n) t += acc[m][n][r] * acc[m][n][r];
#pragma unroll
            for (int off = 1; off <= 8; off <<= 1) t += __shfl_xor(t, off);
            ssq[m][r] = t;
        }
    if (l16 == 0)
#pragma unroll
        for (int m = 0; m < 8; ++m)
#pragma unroll
            for (int r = 0; r < 4; ++r)
                red[((wn & 1) * 2 + headh) * 256 + wm * 128 + m * 16 + quad * 4 + r] =
                    ssq[m][r];
    __syncthreads();

    const bool isQ = bx < 8;
    const float qscl = isQ ? 0.08838834764831845f * 1.4426950408889634f : 1.0f;
    const float* wp = isQ ? qw : kw;
    float wcol[4];
#pragma unroll
    for (int n = 0; n < 4; ++n) wcol[n] = wp[dcol0 + n * 16 + l16];
    u16* dstbase = isQ ? qb + (size_t)(b * 16 + bx * 2 + headh) * 2048 * 128
                       : kb + (size_t)(b * 4 + (bx - 8) * 2 + headh) * 2048 * 128;
    const float sgn = (l16 & 1) ? 1.f : -1.f;

#pragma unroll
    for (int m = 0; m < 8; ++m) {
#pragma unroll
        for (int r = 0; r < 4; ++r) {
            int rowl = wm * 128 + m * 16 + quad * 4 + r;
            float var = (red[(0 + headh) * 256 + rowl] +
                         red[(2 + headh) * 256 + rowl]) * (1.0f / 128.0f);
            float rms = rsqrtf(var + 1.1920928955078125e-07f) * qscl;
            int s = sb + m * 16 + quad * 4 + r;
            const float* fc = fcos + (size_t)s * 128 + dcol0;
            const float* fn = fsin + (size_t)s * 128 + dcol0;
            u16* drow = dstbase + (size_t)s * 128 + dcol0;
#pragma unroll
            for (int n = 0; n < 4; ++n) {
                float y = acc[m][n][r] * rms * wcol[n];
                float yp = __shfl_xor(y, 1);
                float o = y * fc[n * 16 + l16] + sgn * yp * fn[n * 16 + l16];
                drow[n * 16 + l16] = f2bf(o);
            }
        }
    }
}

// ---------------- flash attention v5: K dbuf + V single-buf, 3 blocks/CU ----
// LDS 48.5KB/block -> 3 blocks/CU (12 waves) for latency hiding. V staged
// AFTER the PV-complete barrier (B3), published by vmcnt(4)+B2 next iter.
// FIFO per wave: [V(t), K(t+1)] at B1 -> vmcnt(8); [K(t+1)] at B2 -> vmcnt(4).
#define KBUF(c) ((c) * 8192)
#define VBUF 16384
__global__ __launch_bounds__(256, 3)
void flash_attn(const u16* __restrict__ qb, const u16* __restrict__ kb,
                const u16* __restrict__ vt, u16* __restrict__ ab) {
    __shared__ u16 smem[24576];
    __shared__ float Llds[128];

    const int tid = threadIdx.x;
    const int wave = tid >> 6, lane = tid & 63;
    const int hf = lane >> 5, c32 = lane & 31;
    const int bid = blockIdx.x;
    const int swz = (bid & 7) * 64 + (bid >> 3);
    const int qt = swz & 15, bh = swz >> 4;
    const int hh = bh & 15, bb = bh >> 4;
    const int kh = hh >> 2;

    const u16* Qbase = qb + (size_t)(bb * 16 + hh) * 2048 * 128;
    const u16* Kbase = kb + (size_t)(bb * 4 + kh) * 2048 * 128;
    const u16* Vbase = vt + (size_t)(bb * 4 + kh) * 128 * 2048;

    bf16x8 aq[8];
#pragma unroll
    for (int kq = 0; kq < 8; ++kq)
        aq[kq] = *(const bf16x8*)(Qbase +
            (size_t)(qt * 128 + wave * 32 + c32) * 128 + kq * 16 + hf * 8);

    f32x16 O[4] = {};
    float lacc = 0.f;

    // staging: K tile [64 key][128 d], V tile [128 d][64 key] (key-permuted).
    // LDS chunk pos p holds source chunk p ^ (row&7)  (read XOR matches).
    const int krow = tid >> 4;
    const u16* kg = Kbase + (size_t)krow * 128 + (((tid & 15) ^ (krow & 7)) * 8);
    const int vrow = tid >> 3;
    const u16* vg = Vbase + (size_t)vrow * 2048 + (((tid & 7) ^ (vrow & 7)) * 8);

    auto stageK = [&](int buf, int key0) {
#pragma unroll
        for (int s = 0; s < 4; ++s)
            gload16(kg + key0 * 128 + s * 2048, &smem[KBUF(buf) + s * 2048 + tid * 8]);
    };
    auto stageV = [&](int key0) {
#pragma unroll
        for (int s = 0; s < 4; ++s)
            gload16(vg + (size_t)s * 65536 + key0, &smem[VBUF + s * 2048 + tid * 8]);
    };

    stageK(0, 0);
    stageV(0);

    for (int kt = 0; kt < 32; ++kt) {
        const int cur = kt & 1;
        if (kt < 31) {
            stageK(cur ^ 1, (kt + 1) * 64);
            waitvm<8>();               // K(kt)+V(kt) landed; V(kt)? see vmcnt(4)
        } else {
            waitvm<0>();
        }
        block_sync();                  // B1: publish K(kt)

        f32x16 sc[2] = {};
        __builtin_amdgcn_s_setprio(1);
#pragma unroll
        for (int kq = 0; kq < 8; ++kq) {
#pragma unroll
            for (int mt = 0; mt < 2; ++mt) {
                bf16x8 kf = *(const bf16x8*)&smem[KBUF(cur) + (mt * 32 + c32) * 128 +
                                                 (((kq * 2 + hf) ^ (c32 & 7)) * 8)];
                sc[mt] = __builtin_amdgcn_mfma_f32_32x32x16_bf16(kf, aq[kq], sc[mt], 0, 0, 0);
            }
        }
        __builtin_amdgcn_s_setprio(0);

        int pdw[2][8];
#pragma unroll
        for (int mt = 0; mt < 2; ++mt) {
            float p[16];
#pragma unroll
            for (int r = 0; r < 16; ++r) p[r] = __builtin_amdgcn_exp2f(sc[mt][r]);
            // depth-4 tree sum (cuts the old 32-deep serial add chain)
            float a0 = (p[0] + p[1]) + (p[2] + p[3]);
            float a1 = (p[4] + p[5]) + (p[6] + p[7]);
            float a2 = (p[8] + p[9]) + (p[10] + p[11]);
            float a3 = (p[12] + p[13]) + (p[14] + p[15]);
            lacc += (a0 + a1) + (a2 + a3);
#pragma unroll
            for (int i = 0; i < 8; ++i) pdw[mt][i] = (int)pkbf2(p[2 * i], p[2 * i + 1]);
        }

        if (kt < 31) waitvm<4>();      // V(kt) landed; K(kt+1) stays in flight
        else         waitvm<0>();
        block_sync();                  // B2: publish V(kt)

        __builtin_amdgcn_s_setprio(1);
#pragma unroll
        for (int kc = 0; kc < 4; ++kc) {
            const int mt = kc >> 1, L = kc & 1;
            union { int i[4]; bf16x8 v; } u;
            u.i[0] = pdw[mt][4 * L + 0];
            u.i[1] = pdw[mt][4 * L + 1];
            u.i[2] = pdw[mt][4 * L + 2];
            u.i[3] = pdw[mt][4 * L + 3];
#pragma unroll
            for (int dt = 0; dt < 4; ++dt) {
                bf16x8 vf = *(const bf16x8*)&smem[VBUF + (dt * 32 + c32) * 64 +
                                                 (((kc * 2 + hf) ^ (c32 & 7)) * 8)];
                O[dt] = __builtin_amdgcn_mfma_f32_32x32x16_bf16(u.v, vf, O[dt], 0, 0, 0);
            }
        }
        __builtin_amdgcn_s_setprio(0);
        block_sync();                  // B3: all V reads done -> V buf free
        if (kt < 31) stageV((kt + 1) * 64);
    }

    float l = lacc + __shfl_xor(lacc, 32);
    if (hf == 0) Llds[wave * 32 + c32] = l;

    float inv[16];
#pragma unroll
    for (int r = 0; r < 16; ++r)
        inv[r] = __builtin_amdgcn_rcpf(Llds[wave * 32 + (r & 3) + 8 * (r >> 2) + 4 * hf]);

    u16* scr = &smem[wave * 32 * 136];
#pragma unroll
    for (int dt = 0; dt < 4; ++dt)
#pragma unroll
        for (int r = 0; r < 16; ++r) {
            int q_r = (r & 3) + 8 * (r >> 2) + 4 * hf;
            scr[q_r * 136 + dt * 32 + c32] = f2bf(O[dt][r] * inv[r]);
        }
#pragma unroll
    for (int it = 0; it < 8; ++it) {
        int f = it * 64 + lane;
        int row = f >> 4, c = f & 15;
        u16x8 v = *(const u16x8*)&scr[row * 136 + c * 8];
        int qg = qt * 128 + wave * 32 + row;
        *(u16x8*)(ab + ((size_t)(bb * 2048 + qg)) * 2048 + hh * 128 + c * 8) = v;
    }
}

// ---------------- host launch ----------------
extern "C" void kernel_launch(void* const* d_in, const int* in_sizes, int n_in,
                              void* d_out, int out_size, void* d_ws, size_t ws_size,
                              hipStream_t stream) {
    const float* x    = (const float*)d_in[0];
    const float* wqkv = (const float*)d_in[1];
    const float* wo   = (const float*)d_in[2];
    const float* qw   = (const float*)d_in[3];
    const float* kw   = (const float*)d_in[4];
    const float* fc   = (const float*)d_in[5];
    const float* fs   = (const float*)d_in[6];
    float* out = (float*)d_out;
    char* ws = (char*)d_ws;

    u16* xb    = (u16*)(ws + 0);          // 4096x2048 bf16 (16 MB)
    u16* wqkvb = (u16*)(ws + 16777216);   // 3072x2048 bf16 (12 MB)
    u16* wob   = (u16*)(ws + 29360128);   // 2048x2048 bf16 ( 8 MB)
    u16* qb    = (u16*)(ws + 37748736);   // [2,16,2048,128] (16 MB)
    u16* kb    = (u16*)(ws + 54525952);   // [2,4,2048,128]  ( 4 MB)
    u16* vt    = (u16*)(ws + 58720256);   // [2,4,128,2048]  ( 4 MB, key-permuted)
    u16* ab    = (u16*)(ws + 62914560);   // 4096x2048 bf16  (16 MB)

    cvt_all<<<4608, 256, 0, stream>>>(x, wqkv, wo, xb, wqkvb, wob);
    gemm_qkv<<<192, 512, 0, stream>>>(xb, wqkvb, qw, kw, fc, fs, qb, kb, vt);
    flash_attn<<<512, 256, 0, stream>>>(qb, kb, vt, ab);
    gemm_bt<<<256, 512, 0, stream>>>(ab, wob, out, 4096, 2048, 2048);
}

// Round 12
// 297.713 us; speedup vs baseline: 1.1313x; 1.0079x over previous
//
#include <hip/hip_runtime.h>
#include <hip/hip_bf16.h>

typedef unsigned short u16;
typedef __bf16 bf16x8 __attribute__((ext_vector_type(8)));
typedef __bf16 bf16x4 __attribute__((ext_vector_type(4)));
typedef u16 u16x8 __attribute__((ext_vector_type(8)));
typedef float f32x4 __attribute__((ext_vector_type(4)));
typedef float f32x16 __attribute__((ext_vector_type(16)));

__device__ __forceinline__ u16 f2bf(float f) {
    unsigned u = __float_as_uint(f);
    return (u16)((u + 0x7fffu + ((u >> 16) & 1u)) >> 16);
}
__device__ __forceinline__ unsigned pkbf2(float a, float b) {
    __hip_bfloat162 h = __float22bfloat162_rn(make_float2(a, b));
    return *(unsigned*)&h;
}

// async global->LDS, 16B per lane, LDS dest = wave-uniform base + lane*16
__device__ __forceinline__ void gload16(const u16* g, u16* l) {
    __builtin_amdgcn_global_load_lds(
        (const __attribute__((address_space(1))) void*)g,
        (__attribute__((address_space(3))) void*)l, 16, 0, 0);
}

// raw barrier with compile-time scheduling fence (no vmcnt drain!)
__device__ __forceinline__ void block_sync() {
    __builtin_amdgcn_sched_barrier(0);
    __builtin_amdgcn_s_barrier();
    __builtin_amdgcn_sched_barrier(0);
}
template<int N> __device__ __forceinline__ void waitvm() {
    if constexpr (N == 0)      asm volatile("s_waitcnt vmcnt(0)" ::: "memory");
    else if constexpr (N == 3) asm volatile("s_waitcnt vmcnt(3)" ::: "memory");
    else if constexpr (N == 4) asm volatile("s_waitcnt vmcnt(4)" ::: "memory");
    else if constexpr (N == 6) asm volatile("s_waitcnt vmcnt(6)" ::: "memory");
    else                       asm volatile("s_waitcnt vmcnt(8)" ::: "memory");
}

// ---------------- fp32 -> bf16 convert (x, wqkv, wo fused in one launch) ----
#define CVT_N1 2097152
#define CVT_N2 3670016
#define CVT_TOT 4718592
__global__ void cvt_all(const float* __restrict__ x, const float* __restrict__ wqkv,
                        const float* __restrict__ wo, u16* __restrict__ xb,
                        u16* __restrict__ wqkvb, u16* __restrict__ wob) {
    for (int i = blockIdx.x * 256 + threadIdx.x; i < CVT_TOT; i += 4608 * 256) {
        const float* s; u16* d; int j;
        if (i < CVT_N1)      { s = x;    d = xb;    j = i; }
        else if (i < CVT_N2) { s = wqkv; d = wqkvb; j = i - CVT_N1; }
        else                 { s = wo;   d = wob;   j = i - CVT_N2; }
        float4 v = *(const float4*)(s + (size_t)j * 4);
        uint2 o; o.x = pkbf2(v.x, v.y); o.y = pkbf2(v.z, v.w);
        *(uint2*)(d + (size_t)j * 4) = o;
    }
}

// ---------------- GEMM core v3: BK=32, 3 LDS buffers, ONE barrier/K-tile ----
// Pipeline (steady state, iter t): vmcnt(NLD) proves tile t landed (t+1 still
// in flight) -> barrier (publishes t; also fences all waves past their reads
// of buf t-1) -> issue stage(t+2) into buf (t-1)%3 -> ds_read + MFMA on buf t.
// Loads lead use by 2 K-tiles (~2800 cyc); never drained in the main loop.
// LDS rows are 32 bf16 (64B, 4 chunks of 16B); chunk swizzled by row&3 via
// pre-swizzled global source (linear LDS dest), read with the same XOR.
template<int ROWS>
__device__ __forceinline__ void stage32(const u16* __restrict__ g, int K,
                                        int k0, u16* l, int tid) {
#pragma unroll
    for (int s = 0; s < ROWS / 128; ++s) {
        int row = s * 128 + (tid >> 2);
        int sc = (tid & 3) ^ ((tid >> 2) & 3);
        gload16(g + (size_t)row * K + k0 + sc * 8, l + s * 4096 + tid * 8);
    }
}

template<int BM, int BN>
__device__ __forceinline__ void gemm_pipeline(const u16* __restrict__ Ab,
                                              const u16* __restrict__ Bb, int K,
                                              u16* sAll,
                                              f32x4 (&acc)[BM / 32][BN / 64],
                                              int tid) {
    constexpr int MR = BM / 32, NR = BN / 64;
    constexpr int TILE = (BM + BN) * 32;      // elems per buffer
    constexpr int NLD = (BM + BN) / 128;      // gload16 per wave per tile
    const int lane = tid & 63, wave = tid >> 6;
    const int quad = lane >> 4, l16 = lane & 15;
    const int wm = wave >> 2, wn = wave & 3;
    const int ar0 = wm * (BM / 2) + l16;
    const int br0 = wn * (BN / 4) + l16;

    // prologue: tiles 0,1 -> bufs 0,1
    stage32<BM>(Ab, K, 0, sAll, tid);
    stage32<BN>(Bb, K, 0, sAll + BM * 32, tid);
    stage32<BM>(Ab, K, 32, sAll + TILE, tid);
    stage32<BN>(Bb, K, 32, sAll + TILE + BM * 32, tid);

    const int nt = K >> 5;
    int bufc = 0, bufn = 2;
    for (int t = 0; t < nt; ++t) {
        if (t < nt - 1) waitvm<NLD>();   // tile t landed; t+1 stays in flight
        else            waitvm<0>();
        block_sync();                    // publish tile t; buf (t-1)%3 is free
        if (t + 2 < nt) {
            u16* nb = sAll + bufn * TILE;
            stage32<BM>(Ab, K, (t + 2) * 32, nb, tid);
            stage32<BN>(Bb, K, (t + 2) * 32, nb + BM * 32, tid);
        }
        const u16* cA = sAll + bufc * TILE;
        const u16* cB = cA + BM * 32;
        bf16x8 af[MR], bf[NR];
#pragma unroll
        for (int m = 0; m < MR; ++m) {
            int r = ar0 + m * 16;
            af[m] = *(const bf16x8*)&cA[r * 32 + ((quad ^ (r & 3)) * 8)];
        }
#pragma unroll
        for (int n = 0; n < NR; ++n) {
            int r = br0 + n * 16;
            bf[n] = *(const bf16x8*)&cB[r * 32 + ((quad ^ (r & 3)) * 8)];
        }
        __builtin_amdgcn_s_setprio(1);
#pragma unroll
        for (int m = 0; m < MR; ++m)
#pragma unroll
            for (int n = 0; n < NR; ++n)
                acc[m][n] = __builtin_amdgcn_mfma_f32_16x16x32_bf16(
                    af[m], bf[n], acc[m][n], 0, 0, 0);
        __builtin_amdgcn_s_setprio(0);
        bufc = (bufc == 2) ? 0 : bufc + 1;
        bufn = (bufn == 2) ? 0 : bufn + 1;
    }
}

// ---------------- o-proj GEMM: C = A * B^T, fp32 out (128x256 tile) ---------
__global__ __launch_bounds__(512, 2)
void gemm_bt(const u16* __restrict__ A, const u16* __restrict__ B,
             float* __restrict__ C, int M, int N, int K) {
    __shared__ u16 sAll[3 * (128 + 256) * 32];   // 72 KB
    const int tid = threadIdx.x;
    const int wave = tid >> 6, lane = tid & 63;
    const int quad = lane >> 4, l16 = lane & 15;
    const int wm = wave >> 2, wn = wave & 3;
    const int bid = blockIdx.x;
    const int xcd = bid & 7, r2 = bid >> 3;          // r2 in [0,32)
    const int bni = (xcd & 1) * 4 + (r2 & 3);        // [0,8)
    const int bmi = (xcd >> 1) * 8 + (r2 >> 2);      // [0,32)
    const size_t bm = (size_t)bmi * 128, bn = (size_t)bni * 256;
    f32x4 acc[4][4] = {};
    gemm_pipeline<128, 256>(A + bm * K, B + bn * K, K, sAll, acc, tid);
#pragma unroll
    for (int m = 0; m < 4; ++m)
#pragma unroll
        for (int n = 0; n < 4; ++n)
#pragma unroll
            for (int r = 0; r < 4; ++r)
                C[(bm + wm * 64 + m * 16 + quad * 4 + r) * (size_t)N +
                  bn + wn * 64 + n * 16 + l16] = acc[m][n][r];
}

// ---------------- fused QKV GEMM (256x256): RMSNorm+RoPE (q,k) / transpose (v)
// V is stored KEY-PERMUTED: within each 16-seq group, slot = swap(bits2,3) of
// seq, so flash PV consumes each lane's own QK^T output (no P exchange).
__global__ __launch_bounds__(512, 2)
void gemm_qkv(const u16* __restrict__ xb, const u16* __restrict__ wq,
              const float* __restrict__ qw, const float* __restrict__ kw,
              const float* __restrict__ fcos, const float* __restrict__ fsin,
              u16* __restrict__ qb, u16* __restrict__ kb, u16* __restrict__ vt) {
    __shared__ u16 sAll[3 * (256 + 256) * 32];   // 96 KB
    const int tid = threadIdx.x;
    const int wave = tid >> 6, lane = tid & 63;
    const int quad = lane >> 4, l16 = lane & 15;
    const int wm = wave >> 2, wn = wave & 3;
    const int bid = blockIdx.x;
    const int xcd = bid & 7, r2 = bid >> 3;          // r2 in [0,24)
    const int bx = (xcd & 1) * 6 + r2 % 6;           // [0,12)
    const int by = (xcd >> 1) * 4 + r2 / 6;          // [0,16)
    f32x4 acc[8][4] = {};
    gemm_pipeline<256, 256>(xb + (size_t)by * 256 * 2048,
                            wq + (size_t)bx * 256 * 2048, 2048, sAll, acc, tid);

    const int b = by >> 3;                       // batch
    const int sb = (by & 7) * 256 + wm * 128;    // seq pos base (+m*16+quad*4+r)
    const int headh = wn >> 1;                   // which head of the 2 in tile
    const int dcol0 = (wn & 1) * 64;             // dim base within head (+n*16+l16)

    if (bx >= 10) {
        // V: bf16 transpose store, sigma-permuted quad (1<->2)
        const int qp = ((quad & 1) << 1) | (quad >> 1);
        const int kvh = (bx - 10) * 2 + headh;
        u16* base = vt + (size_t)(b * 4 + kvh) * 128 * 2048;
#pragma unroll
        for (int m = 0; m < 8; ++m) {
            int s0 = sb + m * 16 + qp * 4;
#pragma unroll
            for (int n = 0; n < 4; ++n) {
                int d = dcol0 + n * 16 + l16;
                bf16x4 pv;
#pragma unroll
                for (int r = 0; r < 4; ++r) pv[r] = (__bf16)acc[m][n][r];
                *(bf16x4*)(base + (size_t)d * 2048 + s0) = pv;
            }
        }
        return;
    }

    // Q/K: RMSNorm + RoPE
    float* red = (float*)sAll;   // [parity(2)][headh(2)][row(256)] partial ssq
    float ssq[8][4];
#pragma unroll
    for (int m = 0; m < 8; ++m)
#pragma unroll
        for (int r = 0; r < 4; ++r) {
            float t = 0.f;
#pragma unroll
            for (int n = 0; n < 4; ++n) t += acc[m][n][r] * acc[m][n][r];
#pragma unroll
            for (int off = 1; off <= 8; off <<= 1) t += __shfl_xor(t, off);
            ssq[m][r] = t;
        }
    __syncthreads();
    if (l16 == 0)
#pragma unroll
        for (int m = 0; m < 8; ++m)
#pragma unroll
            for (int r = 0; r < 4; ++r)
                red[((wn & 1) * 2 + headh) * 256 + wm * 128 + m * 16 + quad * 4 + r] =
                    ssq[m][r];
    __syncthreads();

    const bool isQ = bx < 8;
    const float qscl = isQ ? 0.08838834764831845f * 1.4426950408889634f : 1.0f;
    const float* wp = isQ ? qw : kw;
    float wcol[4];
#pragma unroll
    for (int n = 0; n < 4; ++n) wcol[n] = wp[dcol0 + n * 16 + l16];
    u16* dstbase = isQ ? qb + (size_t)(b * 16 + bx * 2 + headh) * 2048 * 128
                       : kb + (size_t)(b * 4 + (bx - 8) * 2 + headh) * 2048 * 128;
    const float sgn = (l16 & 1) ? 1.f : -1.f;

#pragma unroll
    for (int m = 0; m < 8; ++m) {
#pragma unroll
        for (int r = 0; r < 4; ++r) {
            int rowl = wm * 128 + m * 16 + quad * 4 + r;
            float var = (red[(0 + headh) * 256 + rowl] +
                         red[(2 + headh) * 256 + rowl]) * (1.0f / 128.0f);
            float rms = rsqrtf(var + 1.1920928955078125e-07f) * qscl;
            int s = sb + m * 16 + quad * 4 + r;
            const float* fc = fcos + (size_t)s * 128 + dcol0;
            const float* fn = fsin + (size_t)s * 128 + dcol0;
            u16* drow = dstbase + (size_t)s * 128 + dcol0;
#pragma unroll
            for (int n = 0; n < 4; ++n) {
                float y = acc[m][n][r] * rms * wcol[n];
                float yp = __shfl_xor(y, 1);
                float o = y * fc[n * 16 + l16] + sgn * yp * fn[n * 16 + l16];
                drow[n * 16 + l16] = f2bf(o);
            }
        }
    }
}

// ---------------- flash attention v5: K dbuf + V single-buf, 3 blocks/CU ----
#define KBUF(c) ((c) * 8192)
#define VBUF 16384
__global__ __launch_bounds__(256, 3)
void flash_attn(const u16* __restrict__ qb, const u16* __restrict__ kb,
                const u16* __restrict__ vt, u16* __restrict__ ab) {
    __shared__ u16 smem[24576];
    __shared__ float Llds[128];

    const int tid = threadIdx.x;
    const int wave = tid >> 6, lane = tid & 63;
    const int hf = lane >> 5, c32 = lane & 31;
    const int bid = blockIdx.x;
    const int swz = (bid & 7) * 64 + (bid >> 3);
    const int qt = swz & 15, bh = swz >> 4;
    const int hh = bh & 15, bb = bh >> 4;
    const int kh = hh >> 2;

    const u16* Qbase = qb + (size_t)(bb * 16 + hh) * 2048 * 128;
    const u16* Kbase = kb + (size_t)(bb * 4 + kh) * 2048 * 128;
    const u16* Vbase = vt + (size_t)(bb * 4 + kh) * 128 * 2048;

    bf16x8 aq[8];
#pragma unroll
    for (int kq = 0; kq < 8; ++kq)
        aq[kq] = *(const bf16x8*)(Qbase +
            (size_t)(qt * 128 + wave * 32 + c32) * 128 + kq * 16 + hf * 8);

    f32x16 O[4] = {};
    float lacc = 0.f;

    const int krow = tid >> 4;
    const u16* kg = Kbase + (size_t)krow * 128 + (((tid & 15) ^ (krow & 7)) * 8);
    const int vrow = tid >> 3;
    const u16* vg = Vbase + (size_t)vrow * 2048 + (((tid & 7) ^ (vrow & 7)) * 8);

    auto stageK = [&](int buf, int key0) {
#pragma unroll
        for (int s = 0; s < 4; ++s)
            gload16(kg + key0 * 128 + s * 2048, &smem[KBUF(buf) + s * 2048 + tid * 8]);
    };
    auto stageV = [&](int key0) {
#pragma unroll
        for (int s = 0; s < 4; ++s)
            gload16(vg + (size_t)s * 65536 + key0, &smem[VBUF + s * 2048 + tid * 8]);
    };

    stageK(0, 0);
    stageV(0);

    for (int kt = 0; kt < 32; ++kt) {
        const int cur = kt & 1;
        if (kt < 31) {
            stageK(cur ^ 1, (kt + 1) * 64);
            waitvm<8>();               // K(kt)+V(kt) landed; K(kt+1) in flight
        } else {
            waitvm<0>();
        }
        block_sync();                  // B1: publish K(kt)

        f32x16 sc[2] = {};
        __builtin_amdgcn_s_setprio(1);
#pragma unroll
        for (int kq = 0; kq < 8; ++kq) {
#pragma unroll
            for (int mt = 0; mt < 2; ++mt) {
                bf16x8 kf = *(const bf16x8*)&smem[KBUF(cur) + (mt * 32 + c32) * 128 +
                                                 (((kq * 2 + hf) ^ (c32 & 7)) * 8)];
                sc[mt] = __builtin_amdgcn_mfma_f32_32x32x16_bf16(kf, aq[kq], sc[mt], 0, 0, 0);
            }
        }
        __builtin_amdgcn_s_setprio(0);

        int pdw[2][8];
#pragma unroll
        for (int mt = 0; mt < 2; ++mt) {
            float p[16];
#pragma unroll
            for (int r = 0; r < 16; ++r) p[r] = __builtin_amdgcn_exp2f(sc[mt][r]);
            float a0 = (p[0] + p[1]) + (p[2] + p[3]);
            float a1 = (p[4] + p[5]) + (p[6] + p[7]);
            float a2 = (p[8] + p[9]) + (p[10] + p[11]);
            float a3 = (p[12] + p[13]) + (p[14] + p[15]);
            lacc += (a0 + a1) + (a2 + a3);
#pragma unroll
            for (int i = 0; i < 8; ++i) pdw[mt][i] = (int)pkbf2(p[2 * i], p[2 * i + 1]);
        }

        if (kt < 31) waitvm<4>();      // V(kt) landed; K(kt+1) stays in flight
        else         waitvm<0>();
        block_sync();                  // B2: publish V(kt)

        __builtin_amdgcn_s_setprio(1);
#pragma unroll
        for (int kc = 0; kc < 4; ++kc) {
            const int mt = kc >> 1, L = kc & 1;
            union { int i[4]; bf16x8 v; } u;
            u.i[0] = pdw[mt][4 * L + 0];
            u.i[1] = pdw[mt][4 * L + 1];
            u.i[2] = pdw[mt][4 * L + 2];
            u.i[3] = pdw[mt][4 * L + 3];
#pragma unroll
            for (int dt = 0; dt < 4; ++dt) {
                bf16x8 vf = *(const bf16x8*)&smem[VBUF + (dt * 32 + c32) * 64 +
                                                 (((kc * 2 + hf) ^ (c32 & 7)) * 8)];
                O[dt] = __builtin_amdgcn_mfma_f32_32x32x16_bf16(u.v, vf, O[dt], 0, 0, 0);
            }
        }
        __builtin_amdgcn_s_setprio(0);
        block_sync();                  // B3: all V reads done -> V buf free
        if (kt < 31) stageV((kt + 1) * 64);
    }

    float l = lacc + __shfl_xor(lacc, 32);
    if (hf == 0) Llds[wave * 32 + c32] = l;

    float inv[16];
#pragma unroll
    for (int r = 0; r < 16; ++r)
        inv[r] = __builtin_amdgcn_rcpf(Llds[wave * 32 + (r & 3) + 8 * (r >> 2) + 4 * hf]);

    u16* scr = &smem[wave * 32 * 136];
#pragma unroll
    for (int dt = 0; dt < 4; ++dt)
#pragma unroll
        for (int r = 0; r < 16; ++r) {
            int q_r = (r & 3) + 8 * (r >> 2) + 4 * hf;
            scr[q_r * 136 + dt * 32 + c32] = f2bf(O[dt][r] * inv[r]);
        }
#pragma unroll
    for (int it = 0; it < 8; ++it) {
        int f = it * 64 + lane;
        int row = f >> 4, c = f & 15;
        u16x8 v = *(const u16x8*)&scr[row * 136 + c * 8];
        int qg = qt * 128 + wave * 32 + row;
        *(u16x8*)(ab + ((size_t)(bb * 2048 + qg)) * 2048 + hh * 128 + c * 8) = v;
    }
}

// ---------------- host launch ----------------
extern "C" void kernel_launch(void* const* d_in, const int* in_sizes, int n_in,
                              void* d_out, int out_size, void* d_ws, size_t ws_size,
                              hipStream_t stream) {
    const float* x    = (const float*)d_in[0];
    const float* wqkv = (const float*)d_in[1];
    const float* wo   = (const float*)d_in[2];
    const float* qw   = (const float*)d_in[3];
    const float* kw   = (const float*)d_in[4];
    const float* fc   = (const float*)d_in[5];
    const float* fs   = (const float*)d_in[6];
    float* out = (float*)d_out;
    char* ws = (char*)d_ws;

    u16* xb    = (u16*)(ws + 0);          // 4096x2048 bf16 (16 MB)
    u16* wqkvb = (u16*)(ws + 16777216);   // 3072x2048 bf16 (12 MB)
    u16* wob   = (u16*)(ws + 29360128);   // 2048x2048 bf16 ( 8 MB)
    u16* qb    = (u16*)(ws + 37748736);   // [2,16,2048,128] (16 MB)
    u16* kb    = (u16*)(ws + 54525952);   // [2,4,2048,128]  ( 4 MB)
    u16* vt    = (u16*)(ws + 58720256);   // [2,4,128,2048]  ( 4 MB, key-permuted)
    u16* ab    = (u16*)(ws + 62914560);   // 4096x2048 bf16  (16 MB)

    cvt_all<<<4608, 256, 0, stream>>>(x, wqkv, wo, xb, wqkvb, wob);
    gemm_qkv<<<192, 512, 0, stream>>>(xb, wqkvb, qw, kw, fc, fs, qb, kb, vt);
    flash_attn<<<512, 256, 0, stream>>>(qb, kb, vt, ab);
    gemm_bt<<<256, 512, 0, stream>>>(ab, wob, out, 4096, 2048, 2048);
}